// Round 4
// baseline (2996.466 us; speedup 1.0000x reference)
//
#include <hip/hip_runtime.h>

#define N_NODES 50000
#define E_EDGES 800000
#define F 64
#define FE 8
#define H 128
#define MSG_IN 136
#define HPW 68     // dwords per packed-hidden row (node kernel)
#define NXP 136    // ushorts per node sX row (node kernel)

typedef short bf16x8 __attribute__((ext_vector_type(8)));
typedef float f32x4 __attribute__((ext_vector_type(4)));

__device__ __forceinline__ ushort f2bf(float f) {
  uint u = __float_as_uint(f);
  u = (u + 0x7FFFu + ((u >> 16) & 1u)) >> 16;   // RNE
  return (ushort)u;
}
__device__ __forceinline__ uint pack2(float a, float b) {
  return (uint)f2bf(a) | ((uint)f2bf(b) << 16);
}
__device__ __forceinline__ bf16x8 mkfrag(float4 a, float4 b) {
  union { uint u[4]; bf16x8 v; } t;
  t.u[0] = pack2(a.x, a.y); t.u[1] = pack2(a.z, a.w);
  t.u[2] = pack2(b.x, b.y); t.u[3] = pack2(b.z, b.w);
  return t.v;
}

// ---------------------------------------------------------------------------
// Edge pass, barrier-free main loop. Swapped-operand MFMA:
//   D1[j, edge] = W1^T x X^T   (A = W1^T frags in LDS, B = per-lane gathered X)
//   relu+pack in regs -> B-frags for layer 2 (custom k-slot map baked into W2^T)
//   D2[f, edge] = W2^T x hid   -> per-lane atomic scatter.
// b1 folded in at K-slot 136 (X slot = 1.0); b2 via accumulator init.
// Each wave owns an independent 16-edge tile: no __syncthreads in the loop.
// ---------------------------------------------------------------------------
__global__ __launch_bounds__(256, 2)
void edge_pass_mfma(const float* __restrict__ vfeat, const float* __restrict__ cfeat,
                    const float* __restrict__ efeat,
                    const int* __restrict__ ev, const int* __restrict__ ec,
                    const float* __restrict__ w1, const float* __restrict__ b1,
                    const float* __restrict__ w2, const float* __restrict__ b2,
                    float* __restrict__ aggv, float* __restrict__ aggc)
{
  __shared__ __align__(16) ushort sW1T[40 * 512];  // 40960 B: frag (q*5+kb), lane, i
  __shared__ __align__(16) ushort sW2T[16 * 512];  // 16384 B: frag (q2*4+kb), lane, i
  __shared__ float sB2[F];                         // 256 B    -> ~57.6 KB, 2 blocks/CU

  const int t = threadIdx.x;
  const int wid = t >> 6, lane = t & 63;
  const int l15 = lane & 15, hi = lane >> 4;

  // ---- stage W1^T frags: A[m=j=q*16+l15, k=kb*32+hi*8+i]; k==136 -> b1 ----
  for (int idx = t; idx < 40 * 512; idx += 256) {
    const int frag = idx >> 9, rem = idx & 511;
    const int ln = rem >> 3, i = rem & 7;
    const int q = frag / 5, kb = frag % 5;
    const int k = kb * 32 + (ln >> 4) * 8 + i;
    const int col = q * 16 + (ln & 15);
    const float val = (k < MSG_IN) ? w1[k * H + col] : (k == MSG_IN ? b1[col] : 0.f);
    sW1T[idx] = f2bf(val);
  }
  // ---- stage W2^T frags with the packed-hidden slot map:
  //      slot p=hi*8+i  ->  j = kb*32 + (i<4 ? hi*4+i : 16+hi*4+(i-4)) ----
  for (int idx = t; idx < 16 * 512; idx += 256) {
    const int frag = idx >> 9, rem = idx & 511;
    const int ln = rem >> 3, i = rem & 7;
    const int q2 = frag >> 2, kb = frag & 3;
    const int lhi = ln >> 4;
    const int j = kb * 32 + (i < 4 ? lhi * 4 + i : 16 + lhi * 4 + (i - 4));
    sW2T[idx] = f2bf(w2[j * F + q2 * 16 + (ln & 15)]);
  }
  if (t < F) sB2[t] = b2[t];
  __syncthreads();   // only barrier in the kernel

  // b2 accumulator-init vectors (fixed per lane)
  f32x4 binit[4];
  #pragma unroll
  for (int q2 = 0; q2 < 4; ++q2) binit[q2] = *(const f32x4*)&sB2[q2 * 16 + hi * 4];

  constexpr int permB[5] = {2, 3, 0, 1, 4};   // c-side: logical [cs|vs|ef]

  const int NT = E_EDGES / 16;                // 50000
  const int gw = blockIdx.x * 4 + wid;
  const int gstep = gridDim.x * 4;

  int tile = gw;
  int ivC = 0, icC = 0;
  if (tile < NT) { ivC = ev[tile * 16 + l15]; icC = ec[tile * 16 + l15]; }

  for (; tile < NT; tile += gstep) {
    // prefetch next tile's indices early (hides one dependent-load hop)
    const int nt = (tile + gstep < NT) ? tile + gstep : tile;
    const int ivN = ev[nt * 16 + l15];
    const int icN = ec[nt * 16 + l15];

    // ---- per-lane gather of this lane's edge features (B-operand) ----
    const int e = tile * 16 + l15;
    const float4* vp = (const float4*)(vfeat + (size_t)ivC * F);
    const float4* cp = (const float4*)(cfeat + (size_t)icC * F);
    const float4 v0 = vp[hi * 2], v1 = vp[hi * 2 + 1];
    const float4 v2 = vp[8 + hi * 2], v3 = vp[8 + hi * 2 + 1];
    const float4 c0 = cp[hi * 2], c1 = cp[hi * 2 + 1];
    const float4 c2 = cp[8 + hi * 2], c3 = cp[8 + hi * 2 + 1];

    bf16x8 xf[5];
    xf[0] = mkfrag(v0, v1);   // feats hi*8..+7        (vs)
    xf[1] = mkfrag(v2, v3);   // feats 32+hi*8..+7     (vs)
    xf[2] = mkfrag(c0, c1);   // cs
    xf[3] = mkfrag(c2, c3);   // cs
    {
      union { uint u[4]; bf16x8 v; } tmp;
      tmp.u[0] = tmp.u[1] = tmp.u[2] = tmp.u[3] = 0;
      if (hi == 0) {
        const float4* ep = (const float4*)(efeat + (size_t)e * FE);
        const float4 e0 = ep[0], e1 = ep[1];
        tmp.u[0] = pack2(e0.x, e0.y); tmp.u[1] = pack2(e0.z, e0.w);
        tmp.u[2] = pack2(e1.x, e1.y); tmp.u[3] = pack2(e1.z, e1.w);
      } else if (hi == 1) {
        tmp.u[0] = 0x3F80u;   // slot 0 = bf16(1.0) -> logical k=136 (bias row)
      }
      xf[4] = tmp.v;
    }

    // ---- layer 1: D1[j, edge], both sides ----
    f32x4 acc[8][2];
    #pragma unroll
    for (int q = 0; q < 8; ++q) { acc[q][0] = (f32x4)(0.f); acc[q][1] = (f32x4)(0.f); }

    #pragma unroll
    for (int kb = 0; kb < 5; ++kb) {
      const bf16x8 xv = xf[kb];
      const bf16x8 xc = xf[permB[kb]];
      #pragma unroll
      for (int q = 0; q < 8; ++q) {
        const bf16x8 a = *(const bf16x8*)&sW1T[((q * 5 + kb) * 64 + lane) * 8];
        acc[q][0] = __builtin_amdgcn_mfma_f32_16x16x32_bf16(a, xv, acc[q][0], 0, 0, 0);
        acc[q][1] = __builtin_amdgcn_mfma_f32_16x16x32_bf16(a, xc, acc[q][1], 0, 0, 0);
      }
    }

    // ---- relu + pack to layer-2 B-frags, in registers ----
    bf16x8 hf[2][4];
    #pragma unroll
    for (int s = 0; s < 2; ++s)
      #pragma unroll
      for (int kb = 0; kb < 4; ++kb) {
        const f32x4 lo = acc[2 * kb][s], hi4 = acc[2 * kb + 1][s];
        union { uint u[4]; bf16x8 v; } tmp;
        tmp.u[0] = pack2(fmaxf(lo[0], 0.f), fmaxf(lo[1], 0.f));
        tmp.u[1] = pack2(fmaxf(lo[2], 0.f), fmaxf(lo[3], 0.f));
        tmp.u[2] = pack2(fmaxf(hi4[0], 0.f), fmaxf(hi4[1], 0.f));
        tmp.u[3] = pack2(fmaxf(hi4[2], 0.f), fmaxf(hi4[3], 0.f));
        hf[s][kb] = tmp.v;
      }

    // ---- layer 2: D2[f, edge] = W2^T x hid, b2 via init ----
    f32x4 o[2][4];
    #pragma unroll
    for (int q2 = 0; q2 < 4; ++q2) { o[0][q2] = binit[q2]; o[1][q2] = binit[q2]; }

    #pragma unroll
    for (int kb = 0; kb < 4; ++kb)
      #pragma unroll
      for (int q2 = 0; q2 < 4; ++q2) {
        const bf16x8 a = *(const bf16x8*)&sW2T[((q2 * 4 + kb) * 64 + lane) * 8];
        o[0][q2] = __builtin_amdgcn_mfma_f32_16x16x32_bf16(a, hf[0][kb], o[0][q2], 0, 0, 0);
        o[1][q2] = __builtin_amdgcn_mfma_f32_16x16x32_bf16(a, hf[1][kb], o[1][q2], 0, 0, 0);
      }

    // ---- scatter: lane's own edge row; f = q2*16 + hi*4 + r ----
    float* dv = aggv + (size_t)ivC * F + hi * 4;
    float* dc = aggc + (size_t)icC * F + hi * 4;
    #pragma unroll
    for (int q2 = 0; q2 < 4; ++q2)
      #pragma unroll
      for (int r = 0; r < 4; ++r) {
        unsafeAtomicAdd(dv + q2 * 16 + r, o[0][q2][r]);
        unsafeAtomicAdd(dc + q2 * 16 + r, o[1][q2][r]);
      }

    ivC = ivN; icC = icN;
  }
}

// ---------------------------------------------------------------------------
// Node update (bf16 MFMA, unchanged from R3): new_feat = MLP(concat(feat, agg))
// ---------------------------------------------------------------------------
__global__ __launch_bounds__(256, 2)
void node_update_mfma(const float* __restrict__ feat, const float* __restrict__ agg,
                      const float* __restrict__ w1, const float* __restrict__ b1,
                      const float* __restrict__ w2, const float* __restrict__ b2,
                      float* __restrict__ out)
{
  __shared__ __align__(16) ushort sX[64 * NXP];
  __shared__ __align__(16) uint  sH[64 * HPW];

  const int t = threadIdx.x;
  const int wid = t >> 6, l15 = t & 15, hi = (t >> 4) & 3;

  bf16x8 bf1[2][4];
  #pragma unroll
  for (int n = 0; n < 2; ++n) {
    const int col = wid * 32 + n * 16 + l15;
    #pragma unroll
    for (int kb = 0; kb < 4; ++kb)
      #pragma unroll
      for (int i = 0; i < 8; ++i)
        bf1[n][kb][i] = (short)f2bf(w1[(kb * 32 + hi * 8 + i) * H + col]);
  }
  bf16x8 bf2[4][4];
  #pragma unroll
  for (int fb = 0; fb < 4; ++fb) {
    const int col = fb * 16 + l15;
    #pragma unroll
    for (int kb = 0; kb < 4; ++kb)
      #pragma unroll
      for (int i = 0; i < 8; ++i) {
        const int p = hi * 8 + i;
        const int kl = (p >> 1) | ((p & 1) << 4);
        bf2[fb][kb][i] = (short)f2bf(w2[(kb * 32 + kl) * F + col]);
      }
  }
  const float bb1[2] = { b1[wid * 32 + l15], b1[wid * 32 + 16 + l15] };
  const float bb2[4] = { b2[l15], b2[16 + l15], b2[32 + l15], b2[48 + l15] };

  const int r = t >> 2, q = t & 3;
  const int nTiles = (N_NODES + 63) / 64;
  for (int tile = blockIdx.x; tile < nTiles; tile += gridDim.x) {
    __syncthreads();
    {
      const int node = tile * 64 + r;
      const int nc = node < N_NODES ? node : N_NODES - 1;
      const float4* fp = (const float4*)(feat + (size_t)nc * F) + q * 4;
      const float4* ap = (const float4*)(agg  + (size_t)nc * F) + q * 4;
      uint* xr = (uint*)&sX[r * NXP];
      #pragma unroll
      for (int j = 0; j < 4; ++j) {
        const float4 a = fp[j], b = ap[j];
        xr[q * 8 + j * 2]          = pack2(a.x, a.y);
        xr[q * 8 + j * 2 + 1]      = pack2(a.z, a.w);
        xr[32 + q * 8 + j * 2]     = pack2(b.x, b.y);
        xr[32 + q * 8 + j * 2 + 1] = pack2(b.z, b.w);
      }
    }
    __syncthreads();

    f32x4 aV[4][2];
    #pragma unroll
    for (int m = 0; m < 4; ++m)
      #pragma unroll
      for (int n = 0; n < 2; ++n) aV[m][n] = (f32x4)(0.f);
    #pragma unroll
    for (int kb = 0; kb < 4; ++kb)
      #pragma unroll
      for (int m = 0; m < 4; ++m) {
        const bf16x8 a = *(const bf16x8*)&sX[(m * 16 + l15) * NXP + kb * 32 + hi * 8];
        #pragma unroll
        for (int n = 0; n < 2; ++n)
          aV[m][n] = __builtin_amdgcn_mfma_f32_16x16x32_bf16(a, bf1[n][kb], aV[m][n], 0, 0, 0);
      }
    #pragma unroll
    for (int m = 0; m < 4; ++m)
      #pragma unroll
      for (int rr = 0; rr < 4; ++rr) {
        const int e = m * 16 + hi * 4 + rr;
        sH[e * HPW + wid * 16 + l15] =
            pack2(fmaxf(aV[m][0][rr] + bb1[0], 0.f), fmaxf(aV[m][1][rr] + bb1[1], 0.f));
      }
    __syncthreads();

    f32x4 a2[4];
    #pragma unroll
    for (int fb = 0; fb < 4; ++fb) a2[fb] = (f32x4)(0.f);
    const ushort* sHu = (const ushort*)sH;
    #pragma unroll
    for (int kb = 0; kb < 4; ++kb) {
      const int e = wid * 16 + l15;
      const bf16x8 a = *(const bf16x8*)&sHu[e * (HPW * 2) + kb * 32 + hi * 8];
      #pragma unroll
      for (int fb = 0; fb < 4; ++fb)
        a2[fb] = __builtin_amdgcn_mfma_f32_16x16x32_bf16(a, bf2[fb][kb], a2[fb], 0, 0, 0);
    }
    #pragma unroll
    for (int rr = 0; rr < 4; ++rr) {
      const int node = tile * 64 + wid * 16 + hi * 4 + rr;
      if (node < N_NODES) {
        #pragma unroll
        for (int fb = 0; fb < 4; ++fb)
          out[(size_t)node * F + fb * 16 + l15] = a2[fb][rr] + bb2[fb];
      }
    }
  }
}

extern "C" void kernel_launch(void* const* d_in, const int* in_sizes, int n_in,
                              void* d_out, int out_size, void* d_ws, size_t ws_size,
                              hipStream_t stream) {
  const float* var_feat  = (const float*)d_in[0];
  const float* cons_feat = (const float*)d_in[1];
  const float* edge_feat = (const float*)d_in[2];
  const int*   ev        = (const int*)d_in[3];
  const int*   ec        = (const int*)d_in[4];
  const float* w_msg1  = (const float*)d_in[5];
  const float* b_msg1  = (const float*)d_in[6];
  const float* w_msg2  = (const float*)d_in[7];
  const float* b_msg2  = (const float*)d_in[8];
  const float* w_vupd1 = (const float*)d_in[9];
  const float* b_vupd1 = (const float*)d_in[10];
  const float* w_vupd2 = (const float*)d_in[11];
  const float* b_vupd2 = (const float*)d_in[12];
  const float* w_cupd1 = (const float*)d_in[13];
  const float* b_cupd1 = (const float*)d_in[14];
  const float* w_cupd2 = (const float*)d_in[15];
  const float* b_cupd2 = (const float*)d_in[16];

  const size_t NF = (size_t)N_NODES * F;
  float* aggv = (float*)d_ws;
  float* aggc = aggv + NF;
  float* v1   = aggc + NF;
  float* c1   = v1 + NF;
  float* outv = (float*)d_out;
  float* outc = outv + NF;

  for (int it = 0; it < 2; ++it) {
    const float* vf = (it == 0) ? var_feat : v1;
    const float* cf = (it == 0) ? cons_feat : c1;
    float* nv  = (it == 0) ? v1 : outv;
    float* ncs = (it == 0) ? c1 : outc;

    hipMemsetAsync(aggv, 0, NF * sizeof(float), stream);
    hipMemsetAsync(aggc, 0, NF * sizeof(float), stream);

    edge_pass_mfma<<<512, 256, 0, stream>>>(vf, cf, edge_feat, ev, ec,
        w_msg1 + (size_t)it * MSG_IN * H, b_msg1 + (size_t)it * H,
        w_msg2 + (size_t)it * H * F,      b_msg2 + (size_t)it * F,
        aggv, aggc);

    node_update_mfma<<<782, 256, 0, stream>>>(vf, aggv,
        w_vupd1 + (size_t)it * H * H, b_vupd1 + (size_t)it * H,
        w_vupd2 + (size_t)it * H * F, b_vupd2 + (size_t)it * F, nv);

    node_update_mfma<<<782, 256, 0, stream>>>(cf, aggc,
        w_cupd1 + (size_t)it * H * H, b_cupd1 + (size_t)it * H,
        w_cupd2 + (size_t)it * H * F, b_cupd2 + (size_t)it * F, ncs);
  }
}

// Round 5
// 820.071 us; speedup vs baseline: 3.6539x; 3.6539x over previous
//
#include <hip/hip_runtime.h>

#define N_NODES 50000
#define E_EDGES 800000
#define F 64
#define FE 8
#define H 128
#define MSG_IN 136
#define XPAD 168   // ushorts per sX row (K zero-padded 136->160, +8 spread); 336B
#define HPW 68     // dwords per packed-hidden row (64 data + 4 pad); 272B
#define NXP 136    // ushorts per node sX row

typedef short bf16x8 __attribute__((ext_vector_type(8)));
typedef float f32x4 __attribute__((ext_vector_type(4)));

__device__ __forceinline__ ushort f2bf(float f) {
  uint u = __float_as_uint(f);
  u = (u + 0x7FFFu + ((u >> 16) & 1u)) >> 16;   // RNE
  return (ushort)u;
}
__device__ __forceinline__ uint pack2(float a, float b) {
  return (uint)f2bf(a) | ((uint)f2bf(b) << 16);
}

// ---------------------------------------------------------------------------
// Edge pass (bf16 MFMA, R3 dataflow + sequential-side sH for 4 blocks/CU).
// Per 64-edge tile: stage X=[vs|cs|ef] bf16 in LDS (coalesced), layer1 MFMA
// computes BOTH sides into regs; v-hidden -> sH -> layer2-v -> atomics;
// then c-hidden (kept packed in regs) -> sH -> layer2-c -> atomics.
// LDS 39.4KB -> 4 blocks/CU (16 waves) for barrier/latency overlap.
// ---------------------------------------------------------------------------
__global__ __launch_bounds__(256, 4)
void edge_pass_mfma(const float* __restrict__ vfeat, const float* __restrict__ cfeat,
                    const float* __restrict__ efeat,
                    const int* __restrict__ ev, const int* __restrict__ ec,
                    const float* __restrict__ w1, const float* __restrict__ b1,
                    const float* __restrict__ w2, const float* __restrict__ b2,
                    float* __restrict__ aggv, float* __restrict__ aggc)
{
  __shared__ __align__(16) ushort sX[64 * XPAD];   // 21504 B
  __shared__ __align__(16) uint  sH[64 * HPW];     // 17408 B (one side at a time)
  __shared__ int sIv[64], sIc[64];                 // 512 B   => 39424 B total

  const int t = threadIdx.x;
  const int wid = t >> 6, l15 = t & 15, hi = (t >> 4) & 3;
  const int eh = wid >> 1, fh = wid & 1;           // layer2: (edge-half, f-half)

  // ---- layer-1 W1 B-frags: col = wid*32 + n*16 + l15 ----
  bf16x8 bf1[2][5];
  #pragma unroll
  for (int n = 0; n < 2; ++n) {
    const int col = wid * 32 + n * 16 + l15;
    #pragma unroll
    for (int kb = 0; kb < 5; ++kb)
      #pragma unroll
      for (int i = 0; i < 8; ++i) {
        const int kg = kb * 32 + hi * 8 + i;
        bf1[n][kb][i] = (short)((kg < MSG_IN) ? f2bf(w1[kg * H + col]) : (ushort)0);
      }
  }
  // ---- layer-2 W2 B-frags with packed-hidden slot map ----
  bf16x8 bf2[2][4];
  #pragma unroll
  for (int fbl = 0; fbl < 2; ++fbl) {
    const int col = fh * 32 + fbl * 16 + l15;
    #pragma unroll
    for (int kb = 0; kb < 4; ++kb)
      #pragma unroll
      for (int i = 0; i < 8; ++i) {
        const int p = hi * 8 + i;
        const int kl = (p >> 1) | ((p & 1) << 4);
        bf2[fbl][kb][i] = (short)f2bf(w2[(kb * 32 + kl) * F + col]);
      }
  }
  const float bb1[2] = { b1[wid * 32 + l15], b1[wid * 32 + 16 + l15] };
  const float bb2[2] = { b2[fh * 32 + l15], b2[fh * 32 + 16 + l15] };

  // zero the K-pad dwords [68,84) of every sX row (once)
  {
    uint* xu = (uint*)sX;
    for (int i = t; i < 64 * 16; i += 256) {
      const int row = i >> 4, u = i & 15;
      xu[row * (XPAD / 2) + 68 + u] = 0;
    }
  }

  const int r = t >> 2, q = t & 3;
  const int g = gridDim.x;
  const int nTiles = E_EDGES / 64;   // 12500 exact
  int tile = blockIdx.x;             // grid 1024 << 12500: always valid
  int ivC = ev[tile * 64 + r], icC = ec[tile * 64 + r];

  constexpr int perm[5] = {2, 3, 0, 1, 4};   // c-side: logical [cs|vs|ef]

  for (; tile < nTiles; tile += g) {
    // ---- (a) stage X (coalesced 4-lane/row chunks; idx known since last iter)
    {
      const float4* vp = (const float4*)(vfeat + (size_t)ivC * F) + q * 4;
      const float4* cp = (const float4*)(cfeat + (size_t)icC * F) + q * 4;
      uint* xr = (uint*)sX + r * (XPAD / 2);
      #pragma unroll
      for (int j = 0; j < 4; ++j) {
        const float4 v = vp[j], c = cp[j];
        xr[q * 8 + j * 2]          = pack2(v.x, v.y);
        xr[q * 8 + j * 2 + 1]      = pack2(v.z, v.w);
        xr[32 + q * 8 + j * 2]     = pack2(c.x, c.y);
        xr[32 + q * 8 + j * 2 + 1] = pack2(c.z, c.w);
      }
      if (q == 0) {
        const float4* ep = (const float4*)(efeat + (size_t)(tile * 64 + r) * FE);
        const float4 e0 = ep[0], e1 = ep[1];
        xr[64] = pack2(e0.x, e0.y); xr[65] = pack2(e0.z, e0.w);
        xr[66] = pack2(e1.x, e1.y); xr[67] = pack2(e1.z, e1.w);
      }
    }
    // ---- (b) prefetch next tile's indices
    const int nt2 = (tile + g < nTiles) ? tile + g : tile;
    const int ivN = ev[nt2 * 64 + r];
    const int icN = ec[nt2 * 64 + r];
    __syncthreads();                                    // B1
    if (q == 0) { sIv[r] = ivC; sIc[r] = icC; }         // post-B1 (vs f-phase race)

    // ---- (c) layer 1: both sides into regs ----
    f32x4 aV[4][2], aC[4][2];
    #pragma unroll
    for (int m = 0; m < 4; ++m)
      #pragma unroll
      for (int n = 0; n < 2; ++n) { aV[m][n] = (f32x4)(0.f); aC[m][n] = (f32x4)(0.f); }

    #pragma unroll
    for (int kb = 0; kb < 5; ++kb)
      #pragma unroll
      for (int m = 0; m < 4; ++m) {
        const bf16x8 a = *(const bf16x8*)&sX[(m * 16 + l15) * XPAD + kb * 32 + hi * 8];
        #pragma unroll
        for (int n = 0; n < 2; ++n) {
          aV[m][n] = __builtin_amdgcn_mfma_f32_16x16x32_bf16(a, bf1[n][kb],       aV[m][n], 0, 0, 0);
          aC[m][n] = __builtin_amdgcn_mfma_f32_16x16x32_bf16(a, bf1[n][perm[kb]], aC[m][n], 0, 0, 0);
        }
      }

    // v-side -> sH; c-side packed into regs for later
    uint pC[4][4];
    #pragma unroll
    for (int m = 0; m < 4; ++m)
      #pragma unroll
      for (int rr = 0; rr < 4; ++rr) {
        const int e = m * 16 + hi * 4 + rr;
        sH[e * HPW + wid * 16 + l15] =
            pack2(fmaxf(aV[m][0][rr] + bb1[0], 0.f), fmaxf(aV[m][1][rr] + bb1[1], 0.f));
        pC[m][rr] =
            pack2(fmaxf(aC[m][0][rr] + bb1[0], 0.f), fmaxf(aC[m][1][rr] + bb1[1], 0.f));
      }
    __syncthreads();                                    // B2

    // ---- (d) layer 2, v-side: wave owns (edge-half eh, f-half fh) ----
    const ushort* sHu = (const ushort*)sH;
    {
      f32x4 a2[2][2];
      #pragma unroll
      for (int mm = 0; mm < 2; ++mm) { a2[mm][0] = (f32x4)(0.f); a2[mm][1] = (f32x4)(0.f); }
      #pragma unroll
      for (int kb = 0; kb < 4; ++kb)
        #pragma unroll
        for (int mm = 0; mm < 2; ++mm) {
          const int e = (eh * 2 + mm) * 16 + l15;
          const bf16x8 a = *(const bf16x8*)&sHu[e * (HPW * 2) + kb * 32 + hi * 8];
          a2[mm][0] = __builtin_amdgcn_mfma_f32_16x16x32_bf16(a, bf2[0][kb], a2[mm][0], 0, 0, 0);
          a2[mm][1] = __builtin_amdgcn_mfma_f32_16x16x32_bf16(a, bf2[1][kb], a2[mm][1], 0, 0, 0);
        }
      #pragma unroll
      for (int mm = 0; mm < 2; ++mm)
        #pragma unroll
        for (int rr = 0; rr < 4; ++rr) {
          const int idx = sIv[(eh * 2 + mm) * 16 + hi * 4 + rr];
          float* dst = aggv + (size_t)idx * F + fh * 32 + l15;
          unsafeAtomicAdd(dst,      a2[mm][0][rr] + bb2[0]);
          unsafeAtomicAdd(dst + 16, a2[mm][1][rr] + bb2[1]);
        }
    }
    __syncthreads();                                    // B3

    // ---- (e) sH <- c-side hidden ----
    #pragma unroll
    for (int m = 0; m < 4; ++m)
      #pragma unroll
      for (int rr = 0; rr < 4; ++rr)
        sH[(m * 16 + hi * 4 + rr) * HPW + wid * 16 + l15] = pC[m][rr];
    __syncthreads();                                    // B4

    // ---- (f) layer 2, c-side ----
    {
      f32x4 a2[2][2];
      #pragma unroll
      for (int mm = 0; mm < 2; ++mm) { a2[mm][0] = (f32x4)(0.f); a2[mm][1] = (f32x4)(0.f); }
      #pragma unroll
      for (int kb = 0; kb < 4; ++kb)
        #pragma unroll
        for (int mm = 0; mm < 2; ++mm) {
          const int e = (eh * 2 + mm) * 16 + l15;
          const bf16x8 a = *(const bf16x8*)&sHu[e * (HPW * 2) + kb * 32 + hi * 8];
          a2[mm][0] = __builtin_amdgcn_mfma_f32_16x16x32_bf16(a, bf2[0][kb], a2[mm][0], 0, 0, 0);
          a2[mm][1] = __builtin_amdgcn_mfma_f32_16x16x32_bf16(a, bf2[1][kb], a2[mm][1], 0, 0, 0);
        }
      #pragma unroll
      for (int mm = 0; mm < 2; ++mm)
        #pragma unroll
        for (int rr = 0; rr < 4; ++rr) {
          const int idx = sIc[(eh * 2 + mm) * 16 + hi * 4 + rr];
          float* dst = aggc + (size_t)idx * F + fh * 32 + l15;
          unsafeAtomicAdd(dst,      a2[mm][0][rr] + bb2[0]);
          unsafeAtomicAdd(dst + 16, a2[mm][1][rr] + bb2[1]);
        }
    }
    ivC = ivN; icC = icN;
  }
}

// ---------------------------------------------------------------------------
// Node update, both sides in one launch: blocks [0,782) = var, [782,1564) = cons.
// One 64-node tile per block. new_feat = MLP(concat(feat, agg)).
// ---------------------------------------------------------------------------
__global__ __launch_bounds__(256, 2)
void node_update_dual(const float* __restrict__ vfeat, const float* __restrict__ vagg,
                      const float* __restrict__ cfeat, const float* __restrict__ cagg,
                      const float* __restrict__ w1v, const float* __restrict__ b1v,
                      const float* __restrict__ w2v, const float* __restrict__ b2v,
                      const float* __restrict__ w1c, const float* __restrict__ b1c,
                      const float* __restrict__ w2c, const float* __restrict__ b2c,
                      float* __restrict__ outv, float* __restrict__ outc)
{
  __shared__ __align__(16) ushort sX[64 * NXP];
  __shared__ __align__(16) uint  sH[64 * HPW];

  const int half = (N_NODES + 63) / 64;   // 782
  const bool isC = (int)blockIdx.x >= half;
  const int tile = isC ? blockIdx.x - half : blockIdx.x;
  const float* feat = isC ? cfeat : vfeat;
  const float* agg  = isC ? cagg  : vagg;
  const float* w1 = isC ? w1c : w1v;  const float* b1 = isC ? b1c : b1v;
  const float* w2 = isC ? w2c : w2v;  const float* b2 = isC ? b2c : b2v;
  float* out = isC ? outc : outv;

  const int t = threadIdx.x;
  const int wid = t >> 6, l15 = t & 15, hi = (t >> 4) & 3;

  bf16x8 bf1[2][4];
  #pragma unroll
  for (int n = 0; n < 2; ++n) {
    const int col = wid * 32 + n * 16 + l15;
    #pragma unroll
    for (int kb = 0; kb < 4; ++kb)
      #pragma unroll
      for (int i = 0; i < 8; ++i)
        bf1[n][kb][i] = (short)f2bf(w1[(kb * 32 + hi * 8 + i) * H + col]);
  }
  bf16x8 bf2[4][4];
  #pragma unroll
  for (int fb = 0; fb < 4; ++fb) {
    const int col = fb * 16 + l15;
    #pragma unroll
    for (int kb = 0; kb < 4; ++kb)
      #pragma unroll
      for (int i = 0; i < 8; ++i) {
        const int p = hi * 8 + i;
        const int kl = (p >> 1) | ((p & 1) << 4);
        bf2[fb][kb][i] = (short)f2bf(w2[(kb * 32 + kl) * F + col]);
      }
  }
  const float bb1[2] = { b1[wid * 32 + l15], b1[wid * 32 + 16 + l15] };
  const float bb2[4] = { b2[l15], b2[16 + l15], b2[32 + l15], b2[48 + l15] };

  const int r = t >> 2, q = t & 3;
  {
    const int node = tile * 64 + r;
    const int nc = node < N_NODES ? node : N_NODES - 1;
    const float4* fp = (const float4*)(feat + (size_t)nc * F) + q * 4;
    const float4* ap = (const float4*)(agg  + (size_t)nc * F) + q * 4;
    uint* xr = (uint*)&sX[r * NXP];
    #pragma unroll
    for (int j = 0; j < 4; ++j) {
      const float4 a = fp[j], b = ap[j];
      xr[q * 8 + j * 2]          = pack2(a.x, a.y);
      xr[q * 8 + j * 2 + 1]      = pack2(a.z, a.w);
      xr[32 + q * 8 + j * 2]     = pack2(b.x, b.y);
      xr[32 + q * 8 + j * 2 + 1] = pack2(b.z, b.w);
    }
  }
  __syncthreads();

  f32x4 aV[4][2];
  #pragma unroll
  for (int m = 0; m < 4; ++m)
    #pragma unroll
    for (int n = 0; n < 2; ++n) aV[m][n] = (f32x4)(0.f);
  #pragma unroll
  for (int kb = 0; kb < 4; ++kb)
    #pragma unroll
    for (int m = 0; m < 4; ++m) {
      const bf16x8 a = *(const bf16x8*)&sX[(m * 16 + l15) * NXP + kb * 32 + hi * 8];
      #pragma unroll
      for (int n = 0; n < 2; ++n)
        aV[m][n] = __builtin_amdgcn_mfma_f32_16x16x32_bf16(a, bf1[n][kb], aV[m][n], 0, 0, 0);
    }
  #pragma unroll
  for (int m = 0; m < 4; ++m)
    #pragma unroll
    for (int rr = 0; rr < 4; ++rr) {
      const int e = m * 16 + hi * 4 + rr;
      sH[e * HPW + wid * 16 + l15] =
          pack2(fmaxf(aV[m][0][rr] + bb1[0], 0.f), fmaxf(aV[m][1][rr] + bb1[1], 0.f));
    }
  __syncthreads();

  f32x4 a2[4];
  #pragma unroll
  for (int fb = 0; fb < 4; ++fb) a2[fb] = (f32x4)(0.f);
  const ushort* sHu = (const ushort*)sH;
  #pragma unroll
  for (int kb = 0; kb < 4; ++kb) {
    const int e = wid * 16 + l15;
    const bf16x8 a = *(const bf16x8*)&sHu[e * (HPW * 2) + kb * 32 + hi * 8];
    #pragma unroll
    for (int fb = 0; fb < 4; ++fb)
      a2[fb] = __builtin_amdgcn_mfma_f32_16x16x32_bf16(a, bf2[fb][kb], a2[fb], 0, 0, 0);
  }
  #pragma unroll
  for (int rr = 0; rr < 4; ++rr) {
    const int node = tile * 64 + wid * 16 + hi * 4 + rr;
    if (node < N_NODES) {
      #pragma unroll
      for (int fb = 0; fb < 4; ++fb)
        out[(size_t)node * F + fb * 16 + l15] = a2[fb][rr] + bb2[fb];
    }
  }
}

extern "C" void kernel_launch(void* const* d_in, const int* in_sizes, int n_in,
                              void* d_out, int out_size, void* d_ws, size_t ws_size,
                              hipStream_t stream) {
  const float* var_feat  = (const float*)d_in[0];
  const float* cons_feat = (const float*)d_in[1];
  const float* edge_feat = (const float*)d_in[2];
  const int*   ev        = (const int*)d_in[3];
  const int*   ec        = (const int*)d_in[4];
  const float* w_msg1  = (const float*)d_in[5];
  const float* b_msg1  = (const float*)d_in[6];
  const float* w_msg2  = (const float*)d_in[7];
  const float* b_msg2  = (const float*)d_in[8];
  const float* w_vupd1 = (const float*)d_in[9];
  const float* b_vupd1 = (const float*)d_in[10];
  const float* w_vupd2 = (const float*)d_in[11];
  const float* b_vupd2 = (const float*)d_in[12];
  const float* w_cupd1 = (const float*)d_in[13];
  const float* b_cupd1 = (const float*)d_in[14];
  const float* w_cupd2 = (const float*)d_in[15];
  const float* b_cupd2 = (const float*)d_in[16];

  const size_t NF = (size_t)N_NODES * F;
  float* aggv = (float*)d_ws;
  float* aggc = aggv + NF;
  float* v1   = aggc + NF;
  float* c1   = v1 + NF;
  float* outv = (float*)d_out;
  float* outc = outv + NF;

  for (int it = 0; it < 2; ++it) {
    const float* vf = (it == 0) ? var_feat : v1;
    const float* cf = (it == 0) ? cons_feat : c1;
    float* nv  = (it == 0) ? v1 : outv;
    float* ncs = (it == 0) ? c1 : outc;

    hipMemsetAsync(aggv, 0, 2 * NF * sizeof(float), stream);   // aggv+aggc contiguous

    edge_pass_mfma<<<1024, 256, 0, stream>>>(vf, cf, edge_feat, ev, ec,
        w_msg1 + (size_t)it * MSG_IN * H, b_msg1 + (size_t)it * H,
        w_msg2 + (size_t)it * H * F,      b_msg2 + (size_t)it * F,
        aggv, aggc);

    node_update_dual<<<1564, 256, 0, stream>>>(vf, aggv, cf, aggc,
        w_vupd1 + (size_t)it * H * H, b_vupd1 + (size_t)it * H,
        w_vupd2 + (size_t)it * H * F, b_vupd2 + (size_t)it * F,
        w_cupd1 + (size_t)it * H * H, b_cupd1 + (size_t)it * H,
        w_cupd2 + (size_t)it * H * F, b_cupd2 + (size_t)it * F,
        nv, ncs);
  }
}

// Round 6
// 533.003 us; speedup vs baseline: 5.6219x; 1.5386x over previous
//
#include <hip/hip_runtime.h>

#define N_NODES 50000
#define E_EDGES 800000
#define F 64
#define FE 8
#define H 128
#define MSG_IN 136
#define XPAD 168   // ushorts per sX row (K zero-padded 136->160, +8 spread); 336B
#define HPW 68     // dwords per packed-hidden row (64 data + 4 pad); 272B
#define NXP 136    // ushorts per node sX row

typedef short bf16x8 __attribute__((ext_vector_type(8)));
typedef float f32x4 __attribute__((ext_vector_type(4)));

__device__ __forceinline__ ushort f2bf(float f) {
  uint u = __float_as_uint(f);
  u = (u + 0x7FFFu + ((u >> 16) & 1u)) >> 16;   // RNE
  return (ushort)u;
}
__device__ __forceinline__ uint pack2(float a, float b) {
  return (uint)f2bf(a) | ((uint)f2bf(b) << 16);
}
__device__ __forceinline__ void atomic_pk_add_bf16(ushort* addr, uint data) {
  asm volatile("global_atomic_pk_add_bf16 %0, %1, off" :: "v"(addr), "v"(data) : "memory");
}

// ---------------------------------------------------------------------------
// Edge pass (bf16 MFMA). Per 64-edge tile: stage X=[vs|cs|ef] bf16 in LDS
// (coalesced), layer1 MFMA computes BOTH sides into regs; v-hidden -> sH ->
// layer2-v -> packed-bf16 atomics; then c-hidden (kept packed in regs) -> sH
// -> layer2-c -> atomics. Layer-2 n-tile columns remapped so each lane owns
// ADJACENT f-pair (f = fh*32 + 2*l15 + fbl) => one global_atomic_pk_add_bf16
// per pair; 16-lane group = one contiguous 64B line.
// ---------------------------------------------------------------------------
__global__ __launch_bounds__(256, 2)
void edge_pass_mfma(const float* __restrict__ vfeat, const float* __restrict__ cfeat,
                    const float* __restrict__ efeat,
                    const int* __restrict__ ev, const int* __restrict__ ec,
                    const float* __restrict__ w1, const float* __restrict__ b1,
                    const float* __restrict__ w2, const float* __restrict__ b2,
                    ushort* __restrict__ aggv, ushort* __restrict__ aggc)
{
  __shared__ __align__(16) ushort sX[64 * XPAD];   // 21504 B
  __shared__ __align__(16) uint  sH[64 * HPW];     // 17408 B (one side at a time)
  __shared__ int sIv[64], sIc[64];                 // 512 B => 39424 B total

  const int t = threadIdx.x;
  const int wid = t >> 6, l15 = t & 15, hi = (t >> 4) & 3;
  const int eh = wid >> 1, fh = wid & 1;           // layer2: (edge-half, f-half)

  // ---- layer-1 W1 B-frags: col = wid*32 + n*16 + l15 ----
  bf16x8 bf1[2][5];
  #pragma unroll
  for (int n = 0; n < 2; ++n) {
    const int col = wid * 32 + n * 16 + l15;
    #pragma unroll
    for (int kb = 0; kb < 5; ++kb)
      #pragma unroll
      for (int i = 0; i < 8; ++i) {
        const int kg = kb * 32 + hi * 8 + i;
        bf1[n][kb][i] = (short)((kg < MSG_IN) ? f2bf(w1[kg * H + col]) : (ushort)0);
      }
  }
  // ---- layer-2 W2 B-frags: packed-hidden slot map on k, adjacent-f map on n:
  //      n-tile fbl covers f = fh*32 + 2*l15 + fbl  (lane's two outputs adjacent)
  bf16x8 bf2[2][4];
  #pragma unroll
  for (int fbl = 0; fbl < 2; ++fbl) {
    const int col = fh * 32 + 2 * l15 + fbl;
    #pragma unroll
    for (int kb = 0; kb < 4; ++kb)
      #pragma unroll
      for (int i = 0; i < 8; ++i) {
        const int p = hi * 8 + i;
        const int kl = (p >> 1) | ((p & 1) << 4);
        bf2[fbl][kb][i] = (short)f2bf(w2[(kb * 32 + kl) * F + col]);
      }
  }
  const float bb1[2] = { b1[wid * 32 + l15], b1[wid * 32 + 16 + l15] };
  const float bb2[2] = { b2[fh * 32 + 2 * l15], b2[fh * 32 + 2 * l15 + 1] };

  // zero the K-pad dwords [68,84) of every sX row (once)
  {
    uint* xu = (uint*)sX;
    for (int i = t; i < 64 * 16; i += 256) {
      const int row = i >> 4, u = i & 15;
      xu[row * (XPAD / 2) + 68 + u] = 0;
    }
  }

  const int r = t >> 2, q = t & 3;
  const int g = gridDim.x;
  const int nTiles = E_EDGES / 64;   // 12500 exact
  int tile = blockIdx.x;
  int ivC = ev[tile * 64 + r], icC = ec[tile * 64 + r];

  constexpr int perm[5] = {2, 3, 0, 1, 4};   // c-side: logical [cs|vs|ef]

  for (; tile < nTiles; tile += g) {
    // ---- (a) stage X (coalesced 4-lane/row chunks)
    {
      const float4* vp = (const float4*)(vfeat + (size_t)ivC * F) + q * 4;
      const float4* cp = (const float4*)(cfeat + (size_t)icC * F) + q * 4;
      uint* xr = (uint*)sX + r * (XPAD / 2);
      #pragma unroll
      for (int j = 0; j < 4; ++j) {
        const float4 v = vp[j], c = cp[j];
        xr[q * 8 + j * 2]          = pack2(v.x, v.y);
        xr[q * 8 + j * 2 + 1]      = pack2(v.z, v.w);
        xr[32 + q * 8 + j * 2]     = pack2(c.x, c.y);
        xr[32 + q * 8 + j * 2 + 1] = pack2(c.z, c.w);
      }
      if (q == 0) {
        const float4* ep = (const float4*)(efeat + (size_t)(tile * 64 + r) * FE);
        const float4 e0 = ep[0], e1 = ep[1];
        xr[64] = pack2(e0.x, e0.y); xr[65] = pack2(e0.z, e0.w);
        xr[66] = pack2(e1.x, e1.y); xr[67] = pack2(e1.z, e1.w);
      }
    }
    // ---- (b) prefetch next tile's indices
    const int nt2 = (tile + g < nTiles) ? tile + g : tile;
    const int ivN = ev[nt2 * 64 + r];
    const int icN = ec[nt2 * 64 + r];
    __syncthreads();                                    // B1
    if (q == 0) { sIv[r] = ivC; sIc[r] = icC; }

    // ---- (c) layer 1: both sides into regs ----
    f32x4 aV[4][2], aC[4][2];
    #pragma unroll
    for (int m = 0; m < 4; ++m)
      #pragma unroll
      for (int n = 0; n < 2; ++n) { aV[m][n] = (f32x4)(0.f); aC[m][n] = (f32x4)(0.f); }

    #pragma unroll
    for (int kb = 0; kb < 5; ++kb)
      #pragma unroll
      for (int m = 0; m < 4; ++m) {
        const bf16x8 a = *(const bf16x8*)&sX[(m * 16 + l15) * XPAD + kb * 32 + hi * 8];
        #pragma unroll
        for (int n = 0; n < 2; ++n) {
          aV[m][n] = __builtin_amdgcn_mfma_f32_16x16x32_bf16(a, bf1[n][kb],       aV[m][n], 0, 0, 0);
          aC[m][n] = __builtin_amdgcn_mfma_f32_16x16x32_bf16(a, bf1[n][perm[kb]], aC[m][n], 0, 0, 0);
        }
      }

    // v-side -> sH; c-side packed into regs for later
    uint pC[4][4];
    #pragma unroll
    for (int m = 0; m < 4; ++m)
      #pragma unroll
      for (int rr = 0; rr < 4; ++rr) {
        const int e = m * 16 + hi * 4 + rr;
        sH[e * HPW + wid * 16 + l15] =
            pack2(fmaxf(aV[m][0][rr] + bb1[0], 0.f), fmaxf(aV[m][1][rr] + bb1[1], 0.f));
        pC[m][rr] =
            pack2(fmaxf(aC[m][0][rr] + bb1[0], 0.f), fmaxf(aC[m][1][rr] + bb1[1], 0.f));
      }
    __syncthreads();                                    // B2

    // ---- (d) layer 2, v-side ----
    const ushort* sHu = (const ushort*)sH;
    {
      f32x4 a2[2][2];
      #pragma unroll
      for (int mm = 0; mm < 2; ++mm) { a2[mm][0] = (f32x4)(0.f); a2[mm][1] = (f32x4)(0.f); }
      #pragma unroll
      for (int kb = 0; kb < 4; ++kb)
        #pragma unroll
        for (int mm = 0; mm < 2; ++mm) {
          const int e = (eh * 2 + mm) * 16 + l15;
          const bf16x8 a = *(const bf16x8*)&sHu[e * (HPW * 2) + kb * 32 + hi * 8];
          a2[mm][0] = __builtin_amdgcn_mfma_f32_16x16x32_bf16(a, bf2[0][kb], a2[mm][0], 0, 0, 0);
          a2[mm][1] = __builtin_amdgcn_mfma_f32_16x16x32_bf16(a, bf2[1][kb], a2[mm][1], 0, 0, 0);
        }
      #pragma unroll
      for (int mm = 0; mm < 2; ++mm)
        #pragma unroll
        for (int rr = 0; rr < 4; ++rr) {
          const int idx = sIv[(eh * 2 + mm) * 16 + hi * 4 + rr];
          ushort* dst = aggv + (size_t)idx * F + fh * 32 + 2 * l15;
          atomic_pk_add_bf16(dst, pack2(a2[mm][0][rr] + bb2[0], a2[mm][1][rr] + bb2[1]));
        }
    }
    __syncthreads();                                    // B3

    // ---- (e) sH <- c-side hidden ----
    #pragma unroll
    for (int m = 0; m < 4; ++m)
      #pragma unroll
      for (int rr = 0; rr < 4; ++rr)
        sH[(m * 16 + hi * 4 + rr) * HPW + wid * 16 + l15] = pC[m][rr];
    __syncthreads();                                    // B4

    // ---- (f) layer 2, c-side ----
    {
      f32x4 a2[2][2];
      #pragma unroll
      for (int mm = 0; mm < 2; ++mm) { a2[mm][0] = (f32x4)(0.f); a2[mm][1] = (f32x4)(0.f); }
      #pragma unroll
      for (int kb = 0; kb < 4; ++kb)
        #pragma unroll
        for (int mm = 0; mm < 2; ++mm) {
          const int e = (eh * 2 + mm) * 16 + l15;
          const bf16x8 a = *(const bf16x8*)&sHu[e * (HPW * 2) + kb * 32 + hi * 8];
          a2[mm][0] = __builtin_amdgcn_mfma_f32_16x16x32_bf16(a, bf2[0][kb], a2[mm][0], 0, 0, 0);
          a2[mm][1] = __builtin_amdgcn_mfma_f32_16x16x32_bf16(a, bf2[1][kb], a2[mm][1], 0, 0, 0);
        }
      #pragma unroll
      for (int mm = 0; mm < 2; ++mm)
        #pragma unroll
        for (int rr = 0; rr < 4; ++rr) {
          const int idx = sIc[(eh * 2 + mm) * 16 + hi * 4 + rr];
          ushort* dst = aggc + (size_t)idx * F + fh * 32 + 2 * l15;
          atomic_pk_add_bf16(dst, pack2(a2[mm][0][rr] + bb2[0], a2[mm][1][rr] + bb2[1]));
        }
    }
    ivC = ivN; icC = icN;
  }
}

// ---------------------------------------------------------------------------
// Node update, both sides in one launch; agg input is bf16 (copied raw).
// ---------------------------------------------------------------------------
__global__ __launch_bounds__(256, 2)
void node_update_dual(const float* __restrict__ vfeat, const ushort* __restrict__ vagg,
                      const float* __restrict__ cfeat, const ushort* __restrict__ cagg,
                      const float* __restrict__ w1v, const float* __restrict__ b1v,
                      const float* __restrict__ w2v, const float* __restrict__ b2v,
                      const float* __restrict__ w1c, const float* __restrict__ b1c,
                      const float* __restrict__ w2c, const float* __restrict__ b2c,
                      float* __restrict__ outv, float* __restrict__ outc)
{
  __shared__ __align__(16) ushort sX[64 * NXP];
  __shared__ __align__(16) uint  sH[64 * HPW];

  const int half = (N_NODES + 63) / 64;   // 782
  const bool isC = (int)blockIdx.x >= half;
  const int tile = isC ? blockIdx.x - half : blockIdx.x;
  const float* feat = isC ? cfeat : vfeat;
  const ushort* agg = isC ? cagg  : vagg;
  const float* w1 = isC ? w1c : w1v;  const float* b1 = isC ? b1c : b1v;
  const float* w2 = isC ? w2c : w2v;  const float* b2 = isC ? b2c : b2v;
  float* out = isC ? outc : outv;

  const int t = threadIdx.x;
  const int wid = t >> 6, l15 = t & 15, hi = (t >> 4) & 3;

  bf16x8 bf1[2][4];
  #pragma unroll
  for (int n = 0; n < 2; ++n) {
    const int col = wid * 32 + n * 16 + l15;
    #pragma unroll
    for (int kb = 0; kb < 4; ++kb)
      #pragma unroll
      for (int i = 0; i < 8; ++i)
        bf1[n][kb][i] = (short)f2bf(w1[(kb * 32 + hi * 8 + i) * H + col]);
  }
  bf16x8 bf2[4][4];
  #pragma unroll
  for (int fb = 0; fb < 4; ++fb) {
    const int col = fb * 16 + l15;
    #pragma unroll
    for (int kb = 0; kb < 4; ++kb)
      #pragma unroll
      for (int i = 0; i < 8; ++i) {
        const int p = hi * 8 + i;
        const int kl = (p >> 1) | ((p & 1) << 4);
        bf2[fb][kb][i] = (short)f2bf(w2[(kb * 32 + kl) * F + col]);
      }
  }
  const float bb1[2] = { b1[wid * 32 + l15], b1[wid * 32 + 16 + l15] };
  const float bb2[4] = { b2[l15], b2[16 + l15], b2[32 + l15], b2[48 + l15] };

  const int r = t >> 2, q = t & 3;
  {
    const int node = tile * 64 + r;
    const int nc = node < N_NODES ? node : N_NODES - 1;
    const float4* fp = (const float4*)(feat + (size_t)nc * F) + q * 4;
    const uint4*  ap = (const uint4*)(agg + (size_t)nc * F) + q * 2;  // 8 bf16/uint4
    uint* xr = (uint*)&sX[r * NXP];
    #pragma unroll
    for (int j = 0; j < 4; ++j) {
      const float4 a = fp[j];
      xr[q * 8 + j * 2]     = pack2(a.x, a.y);
      xr[q * 8 + j * 2 + 1] = pack2(a.z, a.w);
    }
    #pragma unroll
    for (int j = 0; j < 2; ++j) {
      const uint4 b = ap[j];
      xr[32 + q * 8 + j * 4]     = b.x;
      xr[32 + q * 8 + j * 4 + 1] = b.y;
      xr[32 + q * 8 + j * 4 + 2] = b.z;
      xr[32 + q * 8 + j * 4 + 3] = b.w;
    }
  }
  __syncthreads();

  f32x4 aV[4][2];
  #pragma unroll
  for (int m = 0; m < 4; ++m)
    #pragma unroll
    for (int n = 0; n < 2; ++n) aV[m][n] = (f32x4)(0.f);
  #pragma unroll
  for (int kb = 0; kb < 4; ++kb)
    #pragma unroll
    for (int m = 0; m < 4; ++m) {
      const bf16x8 a = *(const bf16x8*)&sX[(m * 16 + l15) * NXP + kb * 32 + hi * 8];
      #pragma unroll
      for (int n = 0; n < 2; ++n)
        aV[m][n] = __builtin_amdgcn_mfma_f32_16x16x32_bf16(a, bf1[n][kb], aV[m][n], 0, 0, 0);
    }
  #pragma unroll
  for (int m = 0; m < 4; ++m)
    #pragma unroll
    for (int rr = 0; rr < 4; ++rr) {
      const int e = m * 16 + hi * 4 + rr;
      sH[e * HPW + wid * 16 + l15] =
          pack2(fmaxf(aV[m][0][rr] + bb1[0], 0.f), fmaxf(aV[m][1][rr] + bb1[1], 0.f));
    }
  __syncthreads();

  f32x4 a2[4];
  #pragma unroll
  for (int fb = 0; fb < 4; ++fb) a2[fb] = (f32x4)(0.f);
  const ushort* sHu = (const ushort*)sH;
  #pragma unroll
  for (int kb = 0; kb < 4; ++kb) {
    const int e = wid * 16 + l15;
    const bf16x8 a = *(const bf16x8*)&sHu[e * (HPW * 2) + kb * 32 + hi * 8];
    #pragma unroll
    for (int fb = 0; fb < 4; ++fb)
      a2[fb] = __builtin_amdgcn_mfma_f32_16x16x32_bf16(a, bf2[fb][kb], a2[fb], 0, 0, 0);
  }
  #pragma unroll
  for (int rr = 0; rr < 4; ++rr) {
    const int node = tile * 64 + wid * 16 + hi * 4 + rr;
    if (node < N_NODES) {
      #pragma unroll
      for (int fb = 0; fb < 4; ++fb)
        out[(size_t)node * F + fb * 16 + l15] = a2[fb][rr] + bb2[fb];
    }
  }
}

extern "C" void kernel_launch(void* const* d_in, const int* in_sizes, int n_in,
                              void* d_out, int out_size, void* d_ws, size_t ws_size,
                              hipStream_t stream) {
  const float* var_feat  = (const float*)d_in[0];
  const float* cons_feat = (const float*)d_in[1];
  const float* edge_feat = (const float*)d_in[2];
  const int*   ev        = (const int*)d_in[3];
  const int*   ec        = (const int*)d_in[4];
  const float* w_msg1  = (const float*)d_in[5];
  const float* b_msg1  = (const float*)d_in[6];
  const float* w_msg2  = (const float*)d_in[7];
  const float* b_msg2  = (const float*)d_in[8];
  const float* w_vupd1 = (const float*)d_in[9];
  const float* b_vupd1 = (const float*)d_in[10];
  const float* w_vupd2 = (const float*)d_in[11];
  const float* b_vupd2 = (const float*)d_in[12];
  const float* w_cupd1 = (const float*)d_in[13];
  const float* b_cupd1 = (const float*)d_in[14];
  const float* w_cupd2 = (const float*)d_in[15];
  const float* b_cupd2 = (const float*)d_in[16];

  const size_t NF = (size_t)N_NODES * F;
  ushort* aggv = (ushort*)d_ws;          // bf16 agg
  ushort* aggc = aggv + NF;
  float* v1   = (float*)(aggc + NF);
  float* c1   = v1 + NF;
  float* outv = (float*)d_out;
  float* outc = outv + NF;

  for (int it = 0; it < 2; ++it) {
    const float* vf = (it == 0) ? var_feat : v1;
    const float* cf = (it == 0) ? cons_feat : c1;
    float* nv  = (it == 0) ? v1 : outv;
    float* ncs = (it == 0) ? c1 : outc;

    hipMemsetAsync(aggv, 0, 2 * NF * sizeof(ushort), stream);   // bf16 zeros

    edge_pass_mfma<<<768, 256, 0, stream>>>(vf, cf, edge_feat, ev, ec,
        w_msg1 + (size_t)it * MSG_IN * H, b_msg1 + (size_t)it * H,
        w_msg2 + (size_t)it * H * F,      b_msg2 + (size_t)it * F,
        aggv, aggc);

    node_update_dual<<<1564, 256, 0, stream>>>(vf, aggv, cf, aggc,
        w_vupd1 + (size_t)it * H * H, b_vupd1 + (size_t)it * H,
        w_vupd2 + (size_t)it * H * F, b_vupd2 + (size_t)it * F,
        w_cupd1 + (size_t)it * H * H, b_cupd1 + (size_t)it * H,
        w_cupd2 + (size_t)it * H * F, b_cupd2 + (size_t)it * F,
        nv, ncs);
  }
}

// Round 7
// 493.832 us; speedup vs baseline: 6.0678x; 1.0793x over previous
//
#include <hip/hip_runtime.h>

#define N_NODES 50000
#define E_EDGES 800000
#define F 64
#define FE 8
#define H 128
#define MSG_IN 136
#define XPAD 168   // ushorts per sX row (K zero-padded 136->160, +8 spread); 336B
#define HPW 68     // dwords per packed-hidden row (64 data + 4 pad); 272B
#define NXP 136    // ushorts per node sX row (128 data + 8 spread); 272B

typedef short bf16x8 __attribute__((ext_vector_type(8)));
typedef float f32x4 __attribute__((ext_vector_type(4)));

__device__ __forceinline__ ushort f2bf(float f) {
  uint u = __float_as_uint(f);
  u = (u + 0x7FFFu + ((u >> 16) & 1u)) >> 16;   // RNE
  return (ushort)u;
}
__device__ __forceinline__ uint pack2(float a, float b) {
  return (uint)f2bf(a) | ((uint)f2bf(b) << 16);
}
__device__ __forceinline__ void atomic_pk_add_bf16(ushort* addr, uint data) {
  asm volatile("global_atomic_pk_add_bf16 %0, %1, off" :: "v"(addr), "v"(data) : "memory");
}

// ---------------------------------------------------------------------------
// One-time f32 -> bf16 feature conversion (iter 0 inputs).
// ---------------------------------------------------------------------------
__global__ __launch_bounds__(256)
void cvt_feats(const float* __restrict__ a, const float* __restrict__ b,
               ushort* __restrict__ oa, ushort* __restrict__ ob) {
  const int n4 = N_NODES * F / 4;   // 800000 float4-groups per array
  for (int i = blockIdx.x * blockDim.x + threadIdx.x; i < n4; i += gridDim.x * blockDim.x) {
    const float4 va = ((const float4*)a)[i];
    const float4 vb = ((const float4*)b)[i];
    ((uint2*)oa)[i] = make_uint2(pack2(va.x, va.y), pack2(va.z, va.w));
    ((uint2*)ob)[i] = make_uint2(pack2(vb.x, vb.y), pack2(vb.z, vb.w));
  }
}

// ---------------------------------------------------------------------------
// Edge pass (bf16 MFMA). Feats arrive as bf16 -> staging is raw uint4 copies.
// Per 64-edge tile: layer1 MFMA both sides into regs; v-hidden -> sH ->
// layer2-v -> packed-bf16 atomics; c-hidden (regs) -> sH -> layer2-c -> atomics.
// Layer-2 lane owns ADJACENT f-pair => one global_atomic_pk_add_bf16 each.
// LDS 39.4KB, VGPR<=128 target => 4 blocks/CU with grid 1024.
// ---------------------------------------------------------------------------
__global__ __launch_bounds__(256, 2)
void edge_pass_mfma(const ushort* __restrict__ vfeat, const ushort* __restrict__ cfeat,
                    const float* __restrict__ efeat,
                    const int* __restrict__ ev, const int* __restrict__ ec,
                    const float* __restrict__ w1, const float* __restrict__ b1,
                    const float* __restrict__ w2, const float* __restrict__ b2,
                    ushort* __restrict__ aggv, ushort* __restrict__ aggc)
{
  __shared__ __align__(16) ushort sX[64 * XPAD];   // 21504 B
  __shared__ __align__(16) uint  sH[64 * HPW];     // 17408 B (one side at a time)
  __shared__ int sIv[64], sIc[64];                 // 512 B => 39424 B total

  const int t = threadIdx.x;
  const int wid = t >> 6, l15 = t & 15, hi = (t >> 4) & 3;
  const int eh = wid >> 1, fh = wid & 1;           // layer2: (edge-half, f-half)

  // ---- layer-1 W1 B-frags: col = wid*32 + n*16 + l15 ----
  bf16x8 bf1[2][5];
  #pragma unroll
  for (int n = 0; n < 2; ++n) {
    const int col = wid * 32 + n * 16 + l15;
    #pragma unroll
    for (int kb = 0; kb < 5; ++kb)
      #pragma unroll
      for (int i = 0; i < 8; ++i) {
        const int kg = kb * 32 + hi * 8 + i;
        bf1[n][kb][i] = (short)((kg < MSG_IN) ? f2bf(w1[kg * H + col]) : (ushort)0);
      }
  }
  // ---- layer-2 W2 B-frags: packed-hidden slot map on k, adjacent-f map on n
  bf16x8 bf2[2][4];
  #pragma unroll
  for (int fbl = 0; fbl < 2; ++fbl) {
    const int col = fh * 32 + 2 * l15 + fbl;
    #pragma unroll
    for (int kb = 0; kb < 4; ++kb)
      #pragma unroll
      for (int i = 0; i < 8; ++i) {
        const int p = hi * 8 + i;
        const int kl = (p >> 1) | ((p & 1) << 4);
        bf2[fbl][kb][i] = (short)f2bf(w2[(kb * 32 + kl) * F + col]);
      }
  }
  const float bb1[2] = { b1[wid * 32 + l15], b1[wid * 32 + 16 + l15] };
  const float bb2[2] = { b2[fh * 32 + 2 * l15], b2[fh * 32 + 2 * l15 + 1] };

  // zero the K-pad dwords [68,84) of every sX row (once)
  {
    uint* xu = (uint*)sX;
    for (int i = t; i < 64 * 16; i += 256) {
      const int row = i >> 4, u = i & 15;
      xu[row * (XPAD / 2) + 68 + u] = 0;
    }
  }

  const int r = t >> 2, q = t & 3;
  const int g = gridDim.x;
  const int nTiles = E_EDGES / 64;   // 12500 exact
  int tile = blockIdx.x;
  int ivC = ev[tile * 64 + r], icC = ec[tile * 64 + r];

  constexpr int perm[5] = {2, 3, 0, 1, 4};   // c-side: logical [cs|vs|ef]

  for (; tile < nTiles; tile += g) {
    // ---- (a) stage X: raw bf16 row copies, 4 threads/row, ds_write_b128 ----
    {
      const uint4* vp = (const uint4*)(vfeat + (size_t)ivC * F);   // 8 x 16B
      const uint4* cp = (const uint4*)(cfeat + (size_t)icC * F);
      uint4* xr4 = (uint4*)((uint*)sX + r * (XPAD / 2));
      xr4[q * 2]     = vp[q * 2];
      xr4[q * 2 + 1] = vp[q * 2 + 1];
      xr4[8 + q * 2]     = cp[q * 2];
      xr4[8 + q * 2 + 1] = cp[q * 2 + 1];
      if (q == 0) {
        const float4* ep = (const float4*)(efeat + (size_t)(tile * 64 + r) * FE);
        const float4 e0 = ep[0], e1 = ep[1];
        xr4[16] = make_uint4(pack2(e0.x, e0.y), pack2(e0.z, e0.w),
                             pack2(e1.x, e1.y), pack2(e1.z, e1.w));
      }
    }
    // ---- (b) prefetch next tile's indices
    const int nt2 = (tile + g < nTiles) ? tile + g : tile;
    const int ivN = ev[nt2 * 64 + r];
    const int icN = ec[nt2 * 64 + r];
    __syncthreads();                                    // B1
    if (q == 0) { sIv[r] = ivC; sIc[r] = icC; }

    // ---- (c) layer 1: both sides into regs ----
    f32x4 aV[4][2], aC[4][2];
    #pragma unroll
    for (int m = 0; m < 4; ++m)
      #pragma unroll
      for (int n = 0; n < 2; ++n) { aV[m][n] = (f32x4)(0.f); aC[m][n] = (f32x4)(0.f); }

    #pragma unroll
    for (int kb = 0; kb < 5; ++kb)
      #pragma unroll
      for (int m = 0; m < 4; ++m) {
        const bf16x8 a = *(const bf16x8*)&sX[(m * 16 + l15) * XPAD + kb * 32 + hi * 8];
        #pragma unroll
        for (int n = 0; n < 2; ++n) {
          aV[m][n] = __builtin_amdgcn_mfma_f32_16x16x32_bf16(a, bf1[n][kb],       aV[m][n], 0, 0, 0);
          aC[m][n] = __builtin_amdgcn_mfma_f32_16x16x32_bf16(a, bf1[n][perm[kb]], aC[m][n], 0, 0, 0);
        }
      }

    // v-side -> sH; c-side packed into regs for later
    uint pC[4][4];
    #pragma unroll
    for (int m = 0; m < 4; ++m)
      #pragma unroll
      for (int rr = 0; rr < 4; ++rr) {
        const int e = m * 16 + hi * 4 + rr;
        sH[e * HPW + wid * 16 + l15] =
            pack2(fmaxf(aV[m][0][rr] + bb1[0], 0.f), fmaxf(aV[m][1][rr] + bb1[1], 0.f));
        pC[m][rr] =
            pack2(fmaxf(aC[m][0][rr] + bb1[0], 0.f), fmaxf(aC[m][1][rr] + bb1[1], 0.f));
      }
    __syncthreads();                                    // B2

    // ---- (d) layer 2, v-side ----
    const ushort* sHu = (const ushort*)sH;
    {
      f32x4 a2[2][2];
      #pragma unroll
      for (int mm = 0; mm < 2; ++mm) { a2[mm][0] = (f32x4)(0.f); a2[mm][1] = (f32x4)(0.f); }
      #pragma unroll
      for (int kb = 0; kb < 4; ++kb)
        #pragma unroll
        for (int mm = 0; mm < 2; ++mm) {
          const int e = (eh * 2 + mm) * 16 + l15;
          const bf16x8 a = *(const bf16x8*)&sHu[e * (HPW * 2) + kb * 32 + hi * 8];
          a2[mm][0] = __builtin_amdgcn_mfma_f32_16x16x32_bf16(a, bf2[0][kb], a2[mm][0], 0, 0, 0);
          a2[mm][1] = __builtin_amdgcn_mfma_f32_16x16x32_bf16(a, bf2[1][kb], a2[mm][1], 0, 0, 0);
        }
      #pragma unroll
      for (int mm = 0; mm < 2; ++mm)
        #pragma unroll
        for (int rr = 0; rr < 4; ++rr) {
          const int idx = sIv[(eh * 2 + mm) * 16 + hi * 4 + rr];
          ushort* dst = aggv + (size_t)idx * F + fh * 32 + 2 * l15;
          atomic_pk_add_bf16(dst, pack2(a2[mm][0][rr] + bb2[0], a2[mm][1][rr] + bb2[1]));
        }
    }
    __syncthreads();                                    // B3

    // ---- (e) sH <- c-side hidden ----
    #pragma unroll
    for (int m = 0; m < 4; ++m)
      #pragma unroll
      for (int rr = 0; rr < 4; ++rr)
        sH[(m * 16 + hi * 4 + rr) * HPW + wid * 16 + l15] = pC[m][rr];
    __syncthreads();                                    // B4

    // ---- (f) layer 2, c-side ----
    {
      f32x4 a2[2][2];
      #pragma unroll
      for (int mm = 0; mm < 2; ++mm) { a2[mm][0] = (f32x4)(0.f); a2[mm][1] = (f32x4)(0.f); }
      #pragma unroll
      for (int kb = 0; kb < 4; ++kb)
        #pragma unroll
        for (int mm = 0; mm < 2; ++mm) {
          const int e = (eh * 2 + mm) * 16 + l15;
          const bf16x8 a = *(const bf16x8*)&sHu[e * (HPW * 2) + kb * 32 + hi * 8];
          a2[mm][0] = __builtin_amdgcn_mfma_f32_16x16x32_bf16(a, bf2[0][kb], a2[mm][0], 0, 0, 0);
          a2[mm][1] = __builtin_amdgcn_mfma_f32_16x16x32_bf16(a, bf2[1][kb], a2[mm][1], 0, 0, 0);
        }
      #pragma unroll
      for (int mm = 0; mm < 2; ++mm)
        #pragma unroll
        for (int rr = 0; rr < 4; ++rr) {
          const int idx = sIc[(eh * 2 + mm) * 16 + hi * 4 + rr];
          ushort* dst = aggc + (size_t)idx * F + fh * 32 + 2 * l15;
          atomic_pk_add_bf16(dst, pack2(a2[mm][0][rr] + bb2[0], a2[mm][1][rr] + bb2[1]));
        }
    }
    ivC = ivN; icC = icN;
  }
}

// ---------------------------------------------------------------------------
// Node update, both sides in one launch; feat & agg are bf16 (raw staging).
// Updates feat IN PLACE (bf16) for the next iteration; optionally also
// writes f32 output (final iteration).
// ---------------------------------------------------------------------------
__global__ __launch_bounds__(256, 2)
void node_update_dual(ushort* __restrict__ vfeat, const ushort* __restrict__ vagg,
                      ushort* __restrict__ cfeat, const ushort* __restrict__ cagg,
                      const float* __restrict__ w1v, const float* __restrict__ b1v,
                      const float* __restrict__ w2v, const float* __restrict__ b2v,
                      const float* __restrict__ w1c, const float* __restrict__ b1c,
                      const float* __restrict__ w2c, const float* __restrict__ b2c,
                      float* __restrict__ outv, float* __restrict__ outc,
                      int writeF32)
{
  __shared__ __align__(16) ushort sX[64 * NXP];   // 17408 B
  __shared__ __align__(16) uint  sH[64 * HPW];    // 17408 B

  const int half = (N_NODES + 63) / 64;   // 782
  const bool isC = (int)blockIdx.x >= half;
  const int tile = isC ? blockIdx.x - half : blockIdx.x;
  ushort* feat = isC ? cfeat : vfeat;
  const ushort* agg = isC ? cagg : vagg;
  const float* w1 = isC ? w1c : w1v;  const float* b1 = isC ? b1c : b1v;
  const float* w2 = isC ? w2c : w2v;  const float* b2 = isC ? b2c : b2v;
  float* outf = isC ? outc : outv;

  const int t = threadIdx.x;
  const int wid = t >> 6, l15 = t & 15, hi = (t >> 4) & 3;

  bf16x8 bf1[2][4];
  #pragma unroll
  for (int n = 0; n < 2; ++n) {
    const int col = wid * 32 + n * 16 + l15;
    #pragma unroll
    for (int kb = 0; kb < 4; ++kb)
      #pragma unroll
      for (int i = 0; i < 8; ++i)
        bf1[n][kb][i] = (short)f2bf(w1[(kb * 32 + hi * 8 + i) * H + col]);
  }
  // layer-2: lane owns adjacent f-pair per g-half: f = g*32 + 2*l15 + fbl
  bf16x8 bf2[2][2][4];
  #pragma unroll
  for (int gg = 0; gg < 2; ++gg)
    #pragma unroll
    for (int fbl = 0; fbl < 2; ++fbl) {
      const int col = gg * 32 + 2 * l15 + fbl;
      #pragma unroll
      for (int kb = 0; kb < 4; ++kb)
        #pragma unroll
        for (int i = 0; i < 8; ++i) {
          const int p = hi * 8 + i;
          const int kl = (p >> 1) | ((p & 1) << 4);
          bf2[gg][fbl][kb][i] = (short)f2bf(w2[(kb * 32 + kl) * F + col]);
        }
    }
  const float bb1[2] = { b1[wid * 32 + l15], b1[wid * 32 + 16 + l15] };
  float bb2[2][2];
  #pragma unroll
  for (int gg = 0; gg < 2; ++gg) {
    bb2[gg][0] = b2[gg * 32 + 2 * l15];
    bb2[gg][1] = b2[gg * 32 + 2 * l15 + 1];
  }

  const int r = t >> 2, q = t & 3;
  {
    const int node = tile * 64 + r;
    const int nc = node < N_NODES ? node : N_NODES - 1;
    const uint4* fp = (const uint4*)(feat + (size_t)nc * F);
    const uint4* ap = (const uint4*)(agg + (size_t)nc * F);
    uint4* xr4 = (uint4*)&sX[r * NXP];
    xr4[q * 2]     = fp[q * 2];
    xr4[q * 2 + 1] = fp[q * 2 + 1];
    xr4[8 + q * 2]     = ap[q * 2];
    xr4[8 + q * 2 + 1] = ap[q * 2 + 1];
  }
  __syncthreads();

  f32x4 aV[4][2];
  #pragma unroll
  for (int m = 0; m < 4; ++m)
    #pragma unroll
    for (int n = 0; n < 2; ++n) aV[m][n] = (f32x4)(0.f);
  #pragma unroll
  for (int kb = 0; kb < 4; ++kb)
    #pragma unroll
    for (int m = 0; m < 4; ++m) {
      const bf16x8 a = *(const bf16x8*)&sX[(m * 16 + l15) * NXP + kb * 32 + hi * 8];
      #pragma unroll
      for (int n = 0; n < 2; ++n)
        aV[m][n] = __builtin_amdgcn_mfma_f32_16x16x32_bf16(a, bf1[n][kb], aV[m][n], 0, 0, 0);
    }
  #pragma unroll
  for (int m = 0; m < 4; ++m)
    #pragma unroll
    for (int rr = 0; rr < 4; ++rr) {
      const int e = m * 16 + hi * 4 + rr;
      sH[e * HPW + wid * 16 + l15] =
          pack2(fmaxf(aV[m][0][rr] + bb1[0], 0.f), fmaxf(aV[m][1][rr] + bb1[1], 0.f));
    }
  __syncthreads();

  f32x4 a2[2][2];
  #pragma unroll
  for (int gg = 0; gg < 2; ++gg)
    #pragma unroll
    for (int fbl = 0; fbl < 2; ++fbl) a2[gg][fbl] = (f32x4)(0.f);
  const ushort* sHu = (const ushort*)sH;
  #pragma unroll
  for (int kb = 0; kb < 4; ++kb) {
    const int e = wid * 16 + l15;
    const bf16x8 a = *(const bf16x8*)&sHu[e * (HPW * 2) + kb * 32 + hi * 8];
    #pragma unroll
    for (int gg = 0; gg < 2; ++gg)
      #pragma unroll
      for (int fbl = 0; fbl < 2; ++fbl)
        a2[gg][fbl] = __builtin_amdgcn_mfma_f32_16x16x32_bf16(a, bf2[gg][fbl][kb], a2[gg][fbl], 0, 0, 0);
  }
  #pragma unroll
  for (int rr = 0; rr < 4; ++rr) {
    const int node = tile * 64 + wid * 16 + hi * 4 + rr;
    if (node < N_NODES) {
      #pragma unroll
      for (int gg = 0; gg < 2; ++gg) {
        const float o0 = a2[gg][0][rr] + bb2[gg][0];
        const float o1 = a2[gg][1][rr] + bb2[gg][1];
        *(uint*)&feat[(size_t)node * F + gg * 32 + 2 * l15] = pack2(o0, o1);
        if (writeF32) {
          float2 o = make_float2(o0, o1);
          *(float2*)&outf[(size_t)node * F + gg * 32 + 2 * l15] = o;
        }
      }
    }
  }
}

extern "C" void kernel_launch(void* const* d_in, const int* in_sizes, int n_in,
                              void* d_out, int out_size, void* d_ws, size_t ws_size,
                              hipStream_t stream) {
  const float* var_feat  = (const float*)d_in[0];
  const float* cons_feat = (const float*)d_in[1];
  const float* edge_feat = (const float*)d_in[2];
  const int*   ev        = (const int*)d_in[3];
  const int*   ec        = (const int*)d_in[4];
  const float* w_msg1  = (const float*)d_in[5];
  const float* b_msg1  = (const float*)d_in[6];
  const float* w_msg2  = (const float*)d_in[7];
  const float* b_msg2  = (const float*)d_in[8];
  const float* w_vupd1 = (const float*)d_in[9];
  const float* b_vupd1 = (const float*)d_in[10];
  const float* w_vupd2 = (const float*)d_in[11];
  const float* b_vupd2 = (const float*)d_in[12];
  const float* w_cupd1 = (const float*)d_in[13];
  const float* b_cupd1 = (const float*)d_in[14];
  const float* w_cupd2 = (const float*)d_in[15];
  const float* b_cupd2 = (const float*)d_in[16];

  const size_t NF = (size_t)N_NODES * F;
  ushort* aggv = (ushort*)d_ws;          // bf16 agg
  ushort* aggc = aggv + NF;
  ushort* vb   = aggc + NF;              // bf16 features (ping, updated in place)
  ushort* cb   = vb + NF;
  float* outv = (float*)d_out;
  float* outc = outv + NF;

  cvt_feats<<<512, 256, 0, stream>>>(var_feat, cons_feat, vb, cb);

  for (int it = 0; it < 2; ++it) {
    hipMemsetAsync(aggv, 0, 2 * NF * sizeof(ushort), stream);   // bf16 zeros

    edge_pass_mfma<<<1024, 256, 0, stream>>>(vb, cb, edge_feat, ev, ec,
        w_msg1 + (size_t)it * MSG_IN * H, b_msg1 + (size_t)it * H,
        w_msg2 + (size_t)it * H * F,      b_msg2 + (size_t)it * F,
        aggv, aggc);

    node_update_dual<<<1564, 256, 0, stream>>>(vb, aggv, cb, aggc,
        w_vupd1 + (size_t)it * H * H, b_vupd1 + (size_t)it * H,
        w_vupd2 + (size_t)it * H * F, b_vupd2 + (size_t)it * F,
        w_cupd1 + (size_t)it * H * H, b_cupd1 + (size_t)it * H,
        w_cupd2 + (size_t)it * H * F, b_cupd2 + (size_t)it * F,
        outv, outc, it == 1 ? 1 : 0);
  }
}

// Round 8
// 488.921 us; speedup vs baseline: 6.1287x; 1.0100x over previous
//
#include <hip/hip_runtime.h>

#define N_NODES 50000
#define E_EDGES 800000
#define F 64
#define FE 8
#define H 128
#define MSG_IN 136
#define XPAD 168   // ushorts per sX row (K padded 136->160, +8 spread); 336B
#define HPW 68     // dwords per packed-hidden row (64 data + 4 pad); 272B
#define NXP 136    // ushorts per node sX row (128 data + 8 spread); 272B

typedef short bf16x8 __attribute__((ext_vector_type(8)));
typedef float f32x4 __attribute__((ext_vector_type(4)));

// host-side / staging-time scalar conversion (weights, frags)
__device__ __forceinline__ ushort f2bf(float f) {
  uint u = __float_as_uint(f);
  u = (u + 0x7FFFu + ((u >> 16) & 1u)) >> 16;   // RNE
  return (ushort)u;
}
// fast packed conversion: 1 VALU per pair (RNE), gfx950 v_cvt_pk_bf16_f32
__device__ __forceinline__ uint pack2(float lo, float hi) {
  uint r;
  asm("v_cvt_pk_bf16_f32 %0, %1, %2" : "=v"(r) : "v"(lo), "v"(hi));
  return r;
}
__device__ __forceinline__ void atomic_pk_add_bf16(ushort* addr, uint data) {
  asm volatile("global_atomic_pk_add_bf16 %0, %1, off" :: "v"(addr), "v"(data) : "memory");
}

// ---------------------------------------------------------------------------
// One-time f32 -> bf16 feature conversion (iter 0 inputs).
// ---------------------------------------------------------------------------
__global__ __launch_bounds__(256)
void cvt_feats(const float* __restrict__ a, const float* __restrict__ b,
               ushort* __restrict__ oa, ushort* __restrict__ ob) {
  const int n4 = N_NODES * F / 4;
  for (int i = blockIdx.x * blockDim.x + threadIdx.x; i < n4; i += gridDim.x * blockDim.x) {
    const float4 va = ((const float4*)a)[i];
    const float4 vb = ((const float4*)b)[i];
    ((uint2*)oa)[i] = make_uint2(pack2(va.x, va.y), pack2(va.z, va.w));
    ((uint2*)ob)[i] = make_uint2(pack2(vb.x, vb.y), pack2(vb.z, vb.w));
  }
}

// ---------------------------------------------------------------------------
// Edge pass (bf16 MFMA, sequential sides for low reg pressure -> 3 blocks/CU).
// Per 64-edge tile:
//   stage sX=[vs|cs|ef|1.0|0..] (raw bf16 uint4 copies) -> B1
//   layer1-v (40 MFMA, b1 folded via K-slot 136) -> hid-v -> sH (cvt_pk) -> B2
//   layer2-v (16 MFMA) -> packed-bf16 atomics; layer1-c (perm B-frags) -> B3
//   hid-c -> sH -> B4 -> layer2-c -> atomics.
// Lane owns ADJACENT f-pair in layer2 => one global_atomic_pk_add_bf16 each.
// ---------------------------------------------------------------------------
__global__ __launch_bounds__(256, 3)
void edge_pass_mfma(const ushort* __restrict__ vfeat, const ushort* __restrict__ cfeat,
                    const float* __restrict__ efeat,
                    const int* __restrict__ ev, const int* __restrict__ ec,
                    const float* __restrict__ w1, const float* __restrict__ b1,
                    const float* __restrict__ w2, const float* __restrict__ b2,
                    ushort* __restrict__ aggv, ushort* __restrict__ aggc)
{
  __shared__ __align__(16) ushort sX[64 * XPAD];   // 21504 B
  __shared__ __align__(16) uint  sH[64 * HPW];     // 17408 B (one side at a time)
  __shared__ int sIv[64], sIc[64];                 // 512 B => 39424 B total

  const int t = threadIdx.x;
  const int wid = t >> 6, l15 = t & 15, hi = (t >> 4) & 3;
  const int eh = wid >> 1, fh = wid & 1;           // layer2: (edge-half, f-half)

  // ---- layer-1 W1 B-frags: col = wid*32 + n*16 + l15; k==136 -> b1 row ----
  bf16x8 bf1[2][5];
  #pragma unroll
  for (int n = 0; n < 2; ++n) {
    const int col = wid * 32 + n * 16 + l15;
    #pragma unroll
    for (int kb = 0; kb < 5; ++kb)
      #pragma unroll
      for (int i = 0; i < 8; ++i) {
        const int kg = kb * 32 + hi * 8 + i;
        float val = 0.f;
        if (kg < MSG_IN) val = w1[kg * H + col];
        else if (kg == MSG_IN) val = b1[col];
        bf1[n][kb][i] = (short)f2bf(val);
      }
  }
  // ---- layer-2 W2 B-frags: packed-hidden slot map on k, adjacent-f map on n
  bf16x8 bf2[2][4];
  #pragma unroll
  for (int fbl = 0; fbl < 2; ++fbl) {
    const int col = fh * 32 + 2 * l15 + fbl;
    #pragma unroll
    for (int kb = 0; kb < 4; ++kb)
      #pragma unroll
      for (int i = 0; i < 8; ++i) {
        const int p = hi * 8 + i;
        const int kl = (p >> 1) | ((p & 1) << 4);
        bf2[fbl][kb][i] = (short)f2bf(w2[(kb * 32 + kl) * F + col]);
      }
  }
  const float bb2[2] = { b2[fh * 32 + 2 * l15], b2[fh * 32 + 2 * l15 + 1] };

  // pad dwords [68,84): col 136 = bf16(1.0) (bias slot), rest zero (once)
  {
    uint* xu = (uint*)sX;
    for (int i = t; i < 64 * 16; i += 256) {
      const int row = i >> 4, u = i & 15;
      xu[row * (XPAD / 2) + 68 + u] = (u == 0) ? 0x00003F80u : 0u;
    }
  }

  const int r = t >> 2, q = t & 3;
  const int g = gridDim.x;
  const int nTiles = E_EDGES / 64;   // 12500 exact
  int tile = blockIdx.x;
  int ivC = ev[tile * 64 + r], icC = ec[tile * 64 + r];

  constexpr int perm[5] = {2, 3, 0, 1, 4};   // c-side: logical [cs|vs|ef]

  for (; tile < nTiles; tile += g) {
    // ---- (a) stage X: raw bf16 row copies, 4 threads/row ----
    {
      const uint4* vp = (const uint4*)(vfeat + (size_t)ivC * F);
      const uint4* cp = (const uint4*)(cfeat + (size_t)icC * F);
      uint4* xr4 = (uint4*)((uint*)sX + r * (XPAD / 2));
      xr4[q * 2]     = vp[q * 2];
      xr4[q * 2 + 1] = vp[q * 2 + 1];
      xr4[8 + q * 2]     = cp[q * 2];
      xr4[8 + q * 2 + 1] = cp[q * 2 + 1];
      if (q == 0) {
        const float4* ep = (const float4*)(efeat + (size_t)(tile * 64 + r) * FE);
        const float4 e0 = ep[0], e1 = ep[1];
        xr4[16] = make_uint4(pack2(e0.x, e0.y), pack2(e0.z, e0.w),
                             pack2(e1.x, e1.y), pack2(e1.z, e1.w));
      }
    }
    // ---- (b) prefetch next tile's indices
    const int nt2 = (tile + g < nTiles) ? tile + g : tile;
    const int ivN = ev[nt2 * 64 + r];
    const int icN = ec[nt2 * 64 + r];
    __syncthreads();                                    // B1
    if (q == 0) { sIv[r] = ivC; sIc[r] = icC; }

    f32x4 acc[4][2];
    const ushort* sHu = (const ushort*)sH;

    // ---- (c) layer 1, v-side ----
    #pragma unroll
    for (int m = 0; m < 4; ++m)
      #pragma unroll
      for (int n = 0; n < 2; ++n) acc[m][n] = (f32x4)(0.f);
    #pragma unroll
    for (int kb = 0; kb < 5; ++kb)
      #pragma unroll
      for (int m = 0; m < 4; ++m) {
        const bf16x8 a = *(const bf16x8*)&sX[(m * 16 + l15) * XPAD + kb * 32 + hi * 8];
        #pragma unroll
        for (int n = 0; n < 2; ++n)
          acc[m][n] = __builtin_amdgcn_mfma_f32_16x16x32_bf16(a, bf1[n][kb], acc[m][n], 0, 0, 0);
      }
    // hid-v -> sH (relu + cvt_pk; bias already folded)
    #pragma unroll
    for (int m = 0; m < 4; ++m)
      #pragma unroll
      for (int rr = 0; rr < 4; ++rr) {
        const int e = m * 16 + hi * 4 + rr;
        sH[e * HPW + wid * 16 + l15] =
            pack2(fmaxf(acc[m][0][rr], 0.f), fmaxf(acc[m][1][rr], 0.f));
      }
    __syncthreads();                                    // B2

    // ---- (d) layer 2, v-side ----
    {
      f32x4 a2[2][2];
      #pragma unroll
      for (int mm = 0; mm < 2; ++mm) { a2[mm][0] = (f32x4)(0.f); a2[mm][1] = (f32x4)(0.f); }
      #pragma unroll
      for (int kb = 0; kb < 4; ++kb)
        #pragma unroll
        for (int mm = 0; mm < 2; ++mm) {
          const int e = (eh * 2 + mm) * 16 + l15;
          const bf16x8 a = *(const bf16x8*)&sHu[e * (HPW * 2) + kb * 32 + hi * 8];
          a2[mm][0] = __builtin_amdgcn_mfma_f32_16x16x32_bf16(a, bf2[0][kb], a2[mm][0], 0, 0, 0);
          a2[mm][1] = __builtin_amdgcn_mfma_f32_16x16x32_bf16(a, bf2[1][kb], a2[mm][1], 0, 0, 0);
        }
      #pragma unroll
      for (int mm = 0; mm < 2; ++mm)
        #pragma unroll
        for (int rr = 0; rr < 4; ++rr) {
          const int idx = sIv[(eh * 2 + mm) * 16 + hi * 4 + rr];
          ushort* dst = aggv + (size_t)idx * F + fh * 32 + 2 * l15;
          atomic_pk_add_bf16(dst, pack2(a2[mm][0][rr] + bb2[0], a2[mm][1][rr] + bb2[1]));
        }
    }

    // ---- (e) layer 1, c-side (reuse acc; perm'd B-frags; sX still valid) ----
    #pragma unroll
    for (int m = 0; m < 4; ++m)
      #pragma unroll
      for (int n = 0; n < 2; ++n) acc[m][n] = (f32x4)(0.f);
    #pragma unroll
    for (int kb = 0; kb < 5; ++kb)
      #pragma unroll
      for (int m = 0; m < 4; ++m) {
        const bf16x8 a = *(const bf16x8*)&sX[(m * 16 + l15) * XPAD + kb * 32 + hi * 8];
        #pragma unroll
        for (int n = 0; n < 2; ++n)
          acc[m][n] = __builtin_amdgcn_mfma_f32_16x16x32_bf16(a, bf1[n][perm[kb]], acc[m][n], 0, 0, 0);
      }
    __syncthreads();                                    // B3 (all done reading sH-v)
    #pragma unroll
    for (int m = 0; m < 4; ++m)
      #pragma unroll
      for (int rr = 0; rr < 4; ++rr) {
        const int e = m * 16 + hi * 4 + rr;
        sH[e * HPW + wid * 16 + l15] =
            pack2(fmaxf(acc[m][0][rr], 0.f), fmaxf(acc[m][1][rr], 0.f));
      }
    __syncthreads();                                    // B4

    // ---- (f) layer 2, c-side ----
    {
      f32x4 a2[2][2];
      #pragma unroll
      for (int mm = 0; mm < 2; ++mm) { a2[mm][0] = (f32x4)(0.f); a2[mm][1] = (f32x4)(0.f); }
      #pragma unroll
      for (int kb = 0; kb < 4; ++kb)
        #pragma unroll
        for (int mm = 0; mm < 2; ++mm) {
          const int e = (eh * 2 + mm) * 16 + l15;
          const bf16x8 a = *(const bf16x8*)&sHu[e * (HPW * 2) + kb * 32 + hi * 8];
          a2[mm][0] = __builtin_amdgcn_mfma_f32_16x16x32_bf16(a, bf2[0][kb], a2[mm][0], 0, 0, 0);
          a2[mm][1] = __builtin_amdgcn_mfma_f32_16x16x32_bf16(a, bf2[1][kb], a2[mm][1], 0, 0, 0);
        }
      #pragma unroll
      for (int mm = 0; mm < 2; ++mm)
        #pragma unroll
        for (int rr = 0; rr < 4; ++rr) {
          const int idx = sIc[(eh * 2 + mm) * 16 + hi * 4 + rr];
          ushort* dst = aggc + (size_t)idx * F + fh * 32 + 2 * l15;
          atomic_pk_add_bf16(dst, pack2(a2[mm][0][rr] + bb2[0], a2[mm][1][rr] + bb2[1]));
        }
    }
    ivC = ivN; icC = icN;
  }
}

// ---------------------------------------------------------------------------
// Node update, both sides in one launch; feat & agg bf16 (raw staging).
// Updates feat in place (bf16); writes f32 output on final iteration.
// ---------------------------------------------------------------------------
__global__ __launch_bounds__(256, 2)
void node_update_dual(ushort* __restrict__ vfeat, const ushort* __restrict__ vagg,
                      ushort* __restrict__ cfeat, const ushort* __restrict__ cagg,
                      const float* __restrict__ w1v, const float* __restrict__ b1v,
                      const float* __restrict__ w2v, const float* __restrict__ b2v,
                      const float* __restrict__ w1c, const float* __restrict__ b1c,
                      const float* __restrict__ w2c, const float* __restrict__ b2c,
                      float* __restrict__ outv, float* __restrict__ outc,
                      int writeF32)
{
  __shared__ __align__(16) ushort sX[64 * NXP];
  __shared__ __align__(16) uint  sH[64 * HPW];

  const int half = (N_NODES + 63) / 64;   // 782
  const bool isC = (int)blockIdx.x >= half;
  const int tile = isC ? blockIdx.x - half : blockIdx.x;
  ushort* feat = isC ? cfeat : vfeat;
  const ushort* agg = isC ? cagg : vagg;
  const float* w1 = isC ? w1c : w1v;  const float* b1 = isC ? b1c : b1v;
  const float* w2 = isC ? w2c : w2v;  const float* b2 = isC ? b2c : b2v;
  float* outf = isC ? outc : outv;

  const int t = threadIdx.x;
  const int wid = t >> 6, l15 = t & 15, hi = (t >> 4) & 3;

  bf16x8 bf1[2][4];
  #pragma unroll
  for (int n = 0; n < 2; ++n) {
    const int col = wid * 32 + n * 16 + l15;
    #pragma unroll
    for (int kb = 0; kb < 4; ++kb)
      #pragma unroll
      for (int i = 0; i < 8; ++i)
        bf1[n][kb][i] = (short)f2bf(w1[(kb * 32 + hi * 8 + i) * H + col]);
  }
  bf16x8 bf2[2][2][4];
  #pragma unroll
  for (int gg = 0; gg < 2; ++gg)
    #pragma unroll
    for (int fbl = 0; fbl < 2; ++fbl) {
      const int col = gg * 32 + 2 * l15 + fbl;
      #pragma unroll
      for (int kb = 0; kb < 4; ++kb)
        #pragma unroll
        for (int i = 0; i < 8; ++i) {
          const int p = hi * 8 + i;
          const int kl = (p >> 1) | ((p & 1) << 4);
          bf2[gg][fbl][kb][i] = (short)f2bf(w2[(kb * 32 + kl) * F + col]);
        }
    }
  const float bb1[2] = { b1[wid * 32 + l15], b1[wid * 32 + 16 + l15] };
  float bb2[2][2];
  #pragma unroll
  for (int gg = 0; gg < 2; ++gg) {
    bb2[gg][0] = b2[gg * 32 + 2 * l15];
    bb2[gg][1] = b2[gg * 32 + 2 * l15 + 1];
  }

  const int r = t >> 2, q = t & 3;
  {
    const int node = tile * 64 + r;
    const int nc = node < N_NODES ? node : N_NODES - 1;
    const uint4* fp = (const uint4*)(feat + (size_t)nc * F);
    const uint4* ap = (const uint4*)(agg + (size_t)nc * F);
    uint4* xr4 = (uint4*)&sX[r * NXP];
    xr4[q * 2]     = fp[q * 2];
    xr4[q * 2 + 1] = fp[q * 2 + 1];
    xr4[8 + q * 2]     = ap[q * 2];
    xr4[8 + q * 2 + 1] = ap[q * 2 + 1];
  }
  __syncthreads();

  f32x4 aV[4][2];
  #pragma unroll
  for (int m = 0; m < 4; ++m)
    #pragma unroll
    for (int n = 0; n < 2; ++n) aV[m][n] = (f32x4)(0.f);
  #pragma unroll
  for (int kb = 0; kb < 4; ++kb)
    #pragma unroll
    for (int m = 0; m < 4; ++m) {
      const bf16x8 a = *(const bf16x8*)&sX[(m * 16 + l15) * NXP + kb * 32 + hi * 8];
      #pragma unroll
      for (int n = 0; n < 2; ++n)
        aV[m][n] = __builtin_amdgcn_mfma_f32_16x16x32_bf16(a, bf1[n][kb], aV[m][n], 0, 0, 0);
    }
  #pragma unroll
  for (int m = 0; m < 4; ++m)
    #pragma unroll
    for (int rr = 0; rr < 4; ++rr) {
      const int e = m * 16 + hi * 4 + rr;
      sH[e * HPW + wid * 16 + l15] =
          pack2(fmaxf(aV[m][0][rr] + bb1[0], 0.f), fmaxf(aV[m][1][rr] + bb1[1], 0.f));
    }
  __syncthreads();

  f32x4 a2[2][2];
  #pragma unroll
  for (int gg = 0; gg < 2; ++gg)
    #pragma unroll
    for (int fbl = 0; fbl < 2; ++fbl) a2[gg][fbl] = (f32x4)(0.f);
  const ushort* sHu = (const ushort*)sH;
  #pragma unroll
  for (int kb = 0; kb < 4; ++kb) {
    const int e = wid * 16 + l15;
    const bf16x8 a = *(const bf16x8*)&sHu[e * (HPW * 2) + kb * 32 + hi * 8];
    #pragma unroll
    for (int gg = 0; gg < 2; ++gg)
      #pragma unroll
      for (int fbl = 0; fbl < 2; ++fbl)
        a2[gg][fbl] = __builtin_amdgcn_mfma_f32_16x16x32_bf16(a, bf2[gg][fbl][kb], a2[gg][fbl], 0, 0, 0);
  }
  #pragma unroll
  for (int rr = 0; rr < 4; ++rr) {
    const int node = tile * 64 + wid * 16 + hi * 4 + rr;
    if (node < N_NODES) {
      #pragma unroll
      for (int gg = 0; gg < 2; ++gg) {
        const float o0 = a2[gg][0][rr] + bb2[gg][0];
        const float o1 = a2[gg][1][rr] + bb2[gg][1];
        *(uint*)&feat[(size_t)node * F + gg * 32 + 2 * l15] = pack2(o0, o1);
        if (writeF32) {
          float2 o = make_float2(o0, o1);
          *(float2*)&outf[(size_t)node * F + gg * 32 + 2 * l15] = o;
        }
      }
    }
  }
}

extern "C" void kernel_launch(void* const* d_in, const int* in_sizes, int n_in,
                              void* d_out, int out_size, void* d_ws, size_t ws_size,
                              hipStream_t stream) {
  const float* var_feat  = (const float*)d_in[0];
  const float* cons_feat = (const float*)d_in[1];
  const float* edge_feat = (const float*)d_in[2];
  const int*   ev        = (const int*)d_in[3];
  const int*   ec        = (const int*)d_in[4];
  const float* w_msg1  = (const float*)d_in[5];
  const float* b_msg1  = (const float*)d_in[6];
  const float* w_msg2  = (const float*)d_in[7];
  const float* b_msg2  = (const float*)d_in[8];
  const float* w_vupd1 = (const float*)d_in[9];
  const float* b_vupd1 = (const float*)d_in[10];
  const float* w_vupd2 = (const float*)d_in[11];
  const float* b_vupd2 = (const float*)d_in[12];
  const float* w_cupd1 = (const float*)d_in[13];
  const float* b_cupd1 = (const float*)d_in[14];
  const float* w_cupd2 = (const float*)d_in[15];
  const float* b_cupd2 = (const float*)d_in[16];

  const size_t NF = (size_t)N_NODES * F;
  ushort* aggv = (ushort*)d_ws;          // bf16 agg
  ushort* aggc = aggv + NF;
  ushort* vb   = aggc + NF;              // bf16 features (updated in place)
  ushort* cb   = vb + NF;
  float* outv = (float*)d_out;
  float* outc = outv + NF;

  cvt_feats<<<512, 256, 0, stream>>>(var_feat, cons_feat, vb, cb);

  for (int it = 0; it < 2; ++it) {
    hipMemsetAsync(aggv, 0, 2 * NF * sizeof(ushort), stream);

    edge_pass_mfma<<<1024, 256, 0, stream>>>(vb, cb, edge_feat, ev, ec,
        w_msg1 + (size_t)it * MSG_IN * H, b_msg1 + (size_t)it * H,
        w_msg2 + (size_t)it * H * F,      b_msg2 + (size_t)it * F,
        aggv, aggc);

    node_update_dual<<<1564, 256, 0, stream>>>(vb, aggv, cb, aggc,
        w_vupd1 + (size_t)it * H * H, b_vupd1 + (size_t)it * H,
        w_vupd2 + (size_t)it * H * F, b_vupd2 + (size_t)it * F,
        w_cupd1 + (size_t)it * H * H, b_cupd1 + (size_t)it * H,
        w_cupd2 + (size_t)it * H * F, b_cupd2 + (size_t)it * F,
        outv, outc, it == 1 ? 1 : 0);
  }
}

// Round 9
// 421.417 us; speedup vs baseline: 7.1105x; 1.1602x over previous
//
#include <hip/hip_runtime.h>

#define N_NODES 50000
#define E_EDGES 800000
#define F 64
#define FE 8
#define H 128
#define MSG_IN 136
#define XPAD 168   // ushorts per sX row (K padded 136->160, +8 spread); 336B
#define HPW 68     // dwords per packed-hidden row (64 data + 4 pad); 272B
#define NXP 136    // ushorts per node sX row (128 data + 8 spread); 272B

typedef short bf16x8 __attribute__((ext_vector_type(8)));
typedef float f32x4 __attribute__((ext_vector_type(4)));

// staging-time scalar conversion (weights, frags)
__device__ __forceinline__ ushort f2bf(float f) {
  uint u = __float_as_uint(f);
  u = (u + 0x7FFFu + ((u >> 16) & 1u)) >> 16;   // RNE
  return (ushort)u;
}
// fast packed conversion: 1 VALU per pair (RNE), gfx950 v_cvt_pk_bf16_f32
__device__ __forceinline__ uint pack2(float lo, float hi) {
  uint r;
  asm("v_cvt_pk_bf16_f32 %0, %1, %2" : "=v"(r) : "v"(lo), "v"(hi));
  return r;
}
__device__ __forceinline__ void atomic_pk_add_bf16(ushort* addr, uint data) {
  asm volatile("global_atomic_pk_add_bf16 %0, %1, off" :: "v"(addr), "v"(data) : "memory");
}

// ---------------------------------------------------------------------------
// One-time f32 -> bf16 feature conversion (iter 0 inputs).
// ---------------------------------------------------------------------------
__global__ __launch_bounds__(256)
void cvt_feats(const float* __restrict__ a, const float* __restrict__ b,
               ushort* __restrict__ oa, ushort* __restrict__ ob) {
  const int n4 = N_NODES * F / 4;
  for (int i = blockIdx.x * blockDim.x + threadIdx.x; i < n4; i += gridDim.x * blockDim.x) {
    const float4 va = ((const float4*)a)[i];
    const float4 vb = ((const float4*)b)[i];
    ((uint2*)oa)[i] = make_uint2(pack2(va.x, va.y), pack2(va.z, va.w));
    ((uint2*)ob)[i] = make_uint2(pack2(vb.x, vb.y), pack2(vb.z, vb.w));
  }
}

// ---------------------------------------------------------------------------
// Edge pass (bf16 MFMA, 2 barriers/tile + reg-staged prefetch).
// Per 64-edge tile:
//   loop-top: ds_write sX from PREFETCHED regs -> B1
//   issue next tile's feat loads (land during compute)
//   L1-v (40 MFMA) -> hid-v -> sH[0:64); L1-c (40 MFMA, perm'd B) -> sH[64:128)
//   B2 -> L2-v (16 MFMA) -> pk-bf16 atomics; L2-c -> atomics
// b1 folded via K-slot 136 (sX pad col = 1.0). Lane owns adjacent f-pair in
// layer2 => one global_atomic_pk_add_bf16 per pair (64B-line group writes).
// LDS 56.8 KB -> 2 blocks/CU; grid 512 = exactly resident.
// ---------------------------------------------------------------------------
__global__ __launch_bounds__(256, 2)
void edge_pass_mfma(const ushort* __restrict__ vfeat, const ushort* __restrict__ cfeat,
                    const float* __restrict__ efeat,
                    const int* __restrict__ ev, const int* __restrict__ ec,
                    const float* __restrict__ w1, const float* __restrict__ b1,
                    const float* __restrict__ w2, const float* __restrict__ b2,
                    ushort* __restrict__ aggv, ushort* __restrict__ aggc)
{
  __shared__ __align__(16) ushort sX[64 * XPAD];   // 21504 B
  __shared__ __align__(16) uint  sH[128 * HPW];    // 34816 B (v: rows 0-63, c: 64-127)
  __shared__ int sIv[64], sIc[64];                 // 512 B  => 56832 B total

  const int t = threadIdx.x;
  const int wid = t >> 6, l15 = t & 15, hi = (t >> 4) & 3;
  const int eh = wid >> 1, fh = wid & 1;           // layer2: (edge-half, f-half)

  // ---- layer-1 W1 B-frags: col = wid*32 + n*16 + l15; k==136 -> b1 row ----
  bf16x8 bf1[2][5];
  #pragma unroll
  for (int n = 0; n < 2; ++n) {
    const int col = wid * 32 + n * 16 + l15;
    #pragma unroll
    for (int kb = 0; kb < 5; ++kb)
      #pragma unroll
      for (int i = 0; i < 8; ++i) {
        const int kg = kb * 32 + hi * 8 + i;
        float val = 0.f;
        if (kg < MSG_IN) val = w1[kg * H + col];
        else if (kg == MSG_IN) val = b1[col];
        bf1[n][kb][i] = (short)f2bf(val);
      }
  }
  // ---- layer-2 W2 B-frags: packed-hidden slot map on k, adjacent-f map on n
  bf16x8 bf2[2][4];
  #pragma unroll
  for (int fbl = 0; fbl < 2; ++fbl) {
    const int col = fh * 32 + 2 * l15 + fbl;
    #pragma unroll
    for (int kb = 0; kb < 4; ++kb)
      #pragma unroll
      for (int i = 0; i < 8; ++i) {
        const int p = hi * 8 + i;
        const int kl = (p >> 1) | ((p & 1) << 4);
        bf2[fbl][kb][i] = (short)f2bf(w2[(kb * 32 + kl) * F + col]);
      }
  }
  const float bb2[2] = { b2[fh * 32 + 2 * l15], b2[fh * 32 + 2 * l15 + 1] };

  // pad dwords [68,84): col 136 = bf16(1.0) (bias slot), rest zero (once)
  {
    uint* xu = (uint*)sX;
    for (int i = t; i < 64 * 16; i += 256) {
      const int row = i >> 4, u = i & 15;
      xu[row * (XPAD / 2) + 68 + u] = (u == 0) ? 0x00003F80u : 0u;
    }
  }

  const int r = t >> 2, q = t & 3;
  const int g = gridDim.x;
  const int nTiles = E_EDGES / 64;   // 12500 exact
  int tile = blockIdx.x;

  constexpr int perm[5] = {2, 3, 0, 1, 4};   // c-side: logical [cs|vs|ef]

  // ---- prologue: idx(t0) + feats(t0) staged; idx(t1) prefetched ----
  int ivC = ev[tile * 64 + r], icC = ec[tile * 64 + r];
  {
    const int nt = (tile + g < nTiles) ? tile + g : tile;
    // feats(t0)
    const uint4* vp = (const uint4*)(vfeat + (size_t)ivC * F);
    const uint4* cp = (const uint4*)(cfeat + (size_t)icC * F);
    // prefetch idx(t1) into ivN/icN below
  }
  uint4 sv0, sv1, sc0, sc1;
  float4 fe0, fe1;
  {
    const uint4* vp = (const uint4*)(vfeat + (size_t)ivC * F);
    const uint4* cp = (const uint4*)(cfeat + (size_t)icC * F);
    sv0 = vp[q * 2]; sv1 = vp[q * 2 + 1];
    sc0 = cp[q * 2]; sc1 = cp[q * 2 + 1];
    if (q == 0) {
      const float4* ep = (const float4*)(efeat + (size_t)(tile * 64 + r) * FE);
      fe0 = ep[0]; fe1 = ep[1];
    }
  }
  int ivN, icN;
  {
    const int nt = (tile + g < nTiles) ? tile + g : tile;
    ivN = ev[nt * 64 + r]; icN = ec[nt * 64 + r];
  }

  for (; tile < nTiles; tile += g) {
    // ---- (a) sX <- staged regs (loads long since landed) ----
    {
      uint4* xr4 = (uint4*)((uint*)sX + r * (XPAD / 2));
      xr4[q * 2]     = sv0;
      xr4[q * 2 + 1] = sv1;
      xr4[8 + q * 2]     = sc0;
      xr4[8 + q * 2 + 1] = sc1;
      if (q == 0)
        xr4[16] = make_uint4(pack2(fe0.x, fe0.y), pack2(fe0.z, fe0.w),
                             pack2(fe1.x, fe1.y), pack2(fe1.z, fe1.w));
    }
    __syncthreads();                                    // B1: sX ready
    if (q == 0) { sIv[r] = ivC; sIc[r] = icC; }

    // ---- (b) rotate idx; ISSUE next tile's feat loads (hide under compute)
    ivC = ivN; icC = icN;
    {
      const int t2 = (tile + 2 * g < nTiles) ? tile + 2 * g : tile;
      ivN = ev[t2 * 64 + r]; icN = ec[t2 * 64 + r];
      const uint4* vp = (const uint4*)(vfeat + (size_t)ivC * F);
      const uint4* cp = (const uint4*)(cfeat + (size_t)icC * F);
      sv0 = vp[q * 2]; sv1 = vp[q * 2 + 1];
      sc0 = cp[q * 2]; sc1 = cp[q * 2 + 1];
      if (q == 0) {
        const int en = ((tile + g < nTiles) ? tile + g : tile) * 64 + r;
        const float4* ep = (const float4*)(efeat + (size_t)en * FE);
        fe0 = ep[0]; fe1 = ep[1];
      }
    }

    f32x4 acc[4][2];

    // ---- (c) layer 1, v-side -> sH rows [0,64) ----
    #pragma unroll
    for (int m = 0; m < 4; ++m)
      #pragma unroll
      for (int n = 0; n < 2; ++n) acc[m][n] = (f32x4)(0.f);
    #pragma unroll
    for (int kb = 0; kb < 5; ++kb)
      #pragma unroll
      for (int m = 0; m < 4; ++m) {
        const bf16x8 a = *(const bf16x8*)&sX[(m * 16 + l15) * XPAD + kb * 32 + hi * 8];
        #pragma unroll
        for (int n = 0; n < 2; ++n)
          acc[m][n] = __builtin_amdgcn_mfma_f32_16x16x32_bf16(a, bf1[n][kb], acc[m][n], 0, 0, 0);
      }
    #pragma unroll
    for (int m = 0; m < 4; ++m)
      #pragma unroll
      for (int rr = 0; rr < 4; ++rr) {
        const int e = m * 16 + hi * 4 + rr;
        sH[e * HPW + wid * 16 + l15] =
            pack2(fmaxf(acc[m][0][rr], 0.f), fmaxf(acc[m][1][rr], 0.f));
      }

    // ---- (d) layer 1, c-side (perm'd B-frags) -> sH rows [64,128) ----
    #pragma unroll
    for (int m = 0; m < 4; ++m)
      #pragma unroll
      for (int n = 0; n < 2; ++n) acc[m][n] = (f32x4)(0.f);
    #pragma unroll
    for (int kb = 0; kb < 5; ++kb)
      #pragma unroll
      for (int m = 0; m < 4; ++m) {
        const bf16x8 a = *(const bf16x8*)&sX[(m * 16 + l15) * XPAD + kb * 32 + hi * 8];
        #pragma unroll
        for (int n = 0; n < 2; ++n)
          acc[m][n] = __builtin_amdgcn_mfma_f32_16x16x32_bf16(a, bf1[n][perm[kb]], acc[m][n], 0, 0, 0);
      }
    #pragma unroll
    for (int m = 0; m < 4; ++m)
      #pragma unroll
      for (int rr = 0; rr < 4; ++rr) {
        const int e = m * 16 + hi * 4 + rr;
        sH[(64 + e) * HPW + wid * 16 + l15] =
            pack2(fmaxf(acc[m][0][rr], 0.f), fmaxf(acc[m][1][rr], 0.f));
      }
    __syncthreads();                                    // B2: all hid ready

    // ---- (e) layer 2, v-side then c-side; atomics ----
    const ushort* sHu = (const ushort*)sH;
    #pragma unroll
    for (int side = 0; side < 2; ++side) {
      f32x4 a2[2][2];
      #pragma unroll
      for (int mm = 0; mm < 2; ++mm) { a2[mm][0] = (f32x4)(0.f); a2[mm][1] = (f32x4)(0.f); }
      #pragma unroll
      for (int kb = 0; kb < 4; ++kb)
        #pragma unroll
        for (int mm = 0; mm < 2; ++mm) {
          const int e = side * 64 + (eh * 2 + mm) * 16 + l15;
          const bf16x8 a = *(const bf16x8*)&sHu[e * (HPW * 2) + kb * 32 + hi * 8];
          a2[mm][0] = __builtin_amdgcn_mfma_f32_16x16x32_bf16(a, bf2[0][kb], a2[mm][0], 0, 0, 0);
          a2[mm][1] = __builtin_amdgcn_mfma_f32_16x16x32_bf16(a, bf2[1][kb], a2[mm][1], 0, 0, 0);
        }
      ushort* agg = side ? aggc : aggv;
      const int* sI = side ? sIc : sIv;
      #pragma unroll
      for (int mm = 0; mm < 2; ++mm)
        #pragma unroll
        for (int rr = 0; rr < 4; ++rr) {
          const int idx = sI[(eh * 2 + mm) * 16 + hi * 4 + rr];
          ushort* dst = agg + (size_t)idx * F + fh * 32 + 2 * l15;
          atomic_pk_add_bf16(dst, pack2(a2[mm][0][rr] + bb2[0], a2[mm][1][rr] + bb2[1]));
        }
    }
  }
}

// ---------------------------------------------------------------------------
// Node update, both sides in one launch; feat & agg bf16 (raw staging).
// Updates feat in place (bf16); writes f32 output on final iteration.
// ---------------------------------------------------------------------------
__global__ __launch_bounds__(256, 2)
void node_update_dual(ushort* __restrict__ vfeat, const ushort* __restrict__ vagg,
                      ushort* __restrict__ cfeat, const ushort* __restrict__ cagg,
                      const float* __restrict__ w1v, const float* __restrict__ b1v,
                      const float* __restrict__ w2v, const float* __restrict__ b2v,
                      const float* __restrict__ w1c, const float* __restrict__ b1c,
                      const float* __restrict__ w2c, const float* __restrict__ b2c,
                      float* __restrict__ outv, float* __restrict__ outc,
                      int writeF32)
{
  __shared__ __align__(16) ushort sX[64 * NXP];
  __shared__ __align__(16) uint  sH[64 * HPW];

  const int half = (N_NODES + 63) / 64;   // 782
  const bool isC = (int)blockIdx.x >= half;
  const int tile = isC ? blockIdx.x - half : blockIdx.x;
  ushort* feat = isC ? cfeat : vfeat;
  const ushort* agg = isC ? cagg : vagg;
  const float* w1 = isC ? w1c : w1v;  const float* b1 = isC ? b1c : b1v;
  const float* w2 = isC ? w2c : w2v;  const float* b2 = isC ? b2c : b2v;
  float* outf = isC ? outc : outv;

  const int t = threadIdx.x;
  const int wid = t >> 6, l15 = t & 15, hi = (t >> 4) & 3;

  bf16x8 bf1[2][4];
  #pragma unroll
  for (int n = 0; n < 2; ++n) {
    const int col = wid * 32 + n * 16 + l15;
    #pragma unroll
    for (int kb = 0; kb < 4; ++kb)
      #pragma unroll
      for (int i = 0; i < 8; ++i)
        bf1[n][kb][i] = (short)f2bf(w1[(kb * 32 + hi * 8 + i) * H + col]);
  }
  bf16x8 bf2[2][2][4];
  #pragma unroll
  for (int gg = 0; gg < 2; ++gg)
    #pragma unroll
    for (int fbl = 0; fbl < 2; ++fbl) {
      const int col = gg * 32 + 2 * l15 + fbl;
      #pragma unroll
      for (int kb = 0; kb < 4; ++kb)
        #pragma unroll
        for (int i = 0; i < 8; ++i) {
          const int p = hi * 8 + i;
          const int kl = (p >> 1) | ((p & 1) << 4);
          bf2[gg][fbl][kb][i] = (short)f2bf(w2[(kb * 32 + kl) * F + col]);
        }
    }
  const float bb1[2] = { b1[wid * 32 + l15], b1[wid * 32 + 16 + l15] };
  float bb2[2][2];
  #pragma unroll
  for (int gg = 0; gg < 2; ++gg) {
    bb2[gg][0] = b2[gg * 32 + 2 * l15];
    bb2[gg][1] = b2[gg * 32 + 2 * l15 + 1];
  }

  const int r = t >> 2, q = t & 3;
  {
    const int node = tile * 64 + r;
    const int nc = node < N_NODES ? node : N_NODES - 1;
    const uint4* fp = (const uint4*)(feat + (size_t)nc * F);
    const uint4* ap = (const uint4*)(agg + (size_t)nc * F);
    uint4* xr4 = (uint4*)&sX[r * NXP];
    xr4[q * 2]     = fp[q * 2];
    xr4[q * 2 + 1] = fp[q * 2 + 1];
    xr4[8 + q * 2]     = ap[q * 2];
    xr4[8 + q * 2 + 1] = ap[q * 2 + 1];
  }
  __syncthreads();

  f32x4 aV[4][2];
  #pragma unroll
  for (int m = 0; m < 4; ++m)
    #pragma unroll
    for (int n = 0; n < 2; ++n) aV[m][n] = (f32x4)(0.f);
  #pragma unroll
  for (int kb = 0; kb < 4; ++kb)
    #pragma unroll
    for (int m = 0; m < 4; ++m) {
      const bf16x8 a = *(const bf16x8*)&sX[(m * 16 + l15) * NXP + kb * 32 + hi * 8];
      #pragma unroll
      for (int n = 0; n < 2; ++n)
        aV[m][n] = __builtin_amdgcn_mfma_f32_16x16x32_bf16(a, bf1[n][kb], aV[m][n], 0, 0, 0);
    }
  #pragma unroll
  for (int m = 0; m < 4; ++m)
    #pragma unroll
    for (int rr = 0; rr < 4; ++rr) {
      const int e = m * 16 + hi * 4 + rr;
      sH[e * HPW + wid * 16 + l15] =
          pack2(fmaxf(aV[m][0][rr] + bb1[0], 0.f), fmaxf(aV[m][1][rr] + bb1[1], 0.f));
    }
  __syncthreads();

  f32x4 a2[2][2];
  #pragma unroll
  for (int gg = 0; gg < 2; ++gg)
    #pragma unroll
    for (int fbl = 0; fbl < 2; ++fbl) a2[gg][fbl] = (f32x4)(0.f);
  const ushort* sHu = (const ushort*)sH;
  #pragma unroll
  for (int kb = 0; kb < 4; ++kb) {
    const int e = wid * 16 + l15;
    const bf16x8 a = *(const bf16x8*)&sHu[e * (HPW * 2) + kb * 32 + hi * 8];
    #pragma unroll
    for (int gg = 0; gg < 2; ++gg)
      #pragma unroll
      for (int fbl = 0; fbl < 2; ++fbl)
        a2[gg][fbl] = __builtin_amdgcn_mfma_f32_16x16x32_bf16(a, bf2[gg][fbl][kb], a2[gg][fbl], 0, 0, 0);
  }
  #pragma unroll
  for (int rr = 0; rr < 4; ++rr) {
    const int node = tile * 64 + wid * 16 + hi * 4 + rr;
    if (node < N_NODES) {
      #pragma unroll
      for (int gg = 0; gg < 2; ++gg) {
        const float o0 = a2[gg][0][rr] + bb2[gg][0];
        const float o1 = a2[gg][1][rr] + bb2[gg][1];
        *(uint*)&feat[(size_t)node * F + gg * 32 + 2 * l15] = pack2(o0, o1);
        if (writeF32) {
          float2 o = make_float2(o0, o1);
          *(float2*)&outf[(size_t)node * F + gg * 32 + 2 * l15] = o;
        }
      }
    }
  }
}

extern "C" void kernel_launch(void* const* d_in, const int* in_sizes, int n_in,
                              void* d_out, int out_size, void* d_ws, size_t ws_size,
                              hipStream_t stream) {
  const float* var_feat  = (const float*)d_in[0];
  const float* cons_feat = (const float*)d_in[1];
  const float* edge_feat = (const float*)d_in[2];
  const int*   ev        = (const int*)d_in[3];
  const int*   ec        = (const int*)d_in[4];
  const float* w_msg1  = (const float*)d_in[5];
  const float* b_msg1  = (const float*)d_in[6];
  const float* w_msg2  = (const float*)d_in[7];
  const float* b_msg2  = (const float*)d_in[8];
  const float* w_vupd1 = (const float*)d_in[9];
  const float* b_vupd1 = (const float*)d_in[10];
  const float* w_vupd2 = (const float*)d_in[11];
  const float* b_vupd2 = (const float*)d_in[12];
  const float* w_cupd1 = (const float*)d_in[13];
  const float* b_cupd1 = (const float*)d_in[14];
  const float* w_cupd2 = (const float*)d_in[15];
  const float* b_cupd2 = (const float*)d_in[16];

  const size_t NF = (size_t)N_NODES * F;
  ushort* aggv = (ushort*)d_ws;          // bf16 agg
  ushort* aggc = aggv + NF;
  ushort* vb   = aggc + NF;              // bf16 features (updated in place)
  ushort* cb   = vb + NF;
  float* outv = (float*)d_out;
  float* outc = outv + NF;

  cvt_feats<<<512, 256, 0, stream>>>(var_feat, cons_feat, vb, cb);

  for (int it = 0; it < 2; ++it) {
    hipMemsetAsync(aggv, 0, 2 * NF * sizeof(ushort), stream);

    edge_pass_mfma<<<512, 256, 0, stream>>>(vb, cb, edge_feat, ev, ec,
        w_msg1 + (size_t)it * MSG_IN * H, b_msg1 + (size_t)it * H,
        w_msg2 + (size_t)it * H * F,      b_msg2 + (size_t)it * F,
        aggv, aggc);

    node_update_dual<<<1564, 256, 0, stream>>>(vb, aggv, cb, aggc,
        w_vupd1 + (size_t)it * H * H, b_vupd1 + (size_t)it * H,
        w_vupd2 + (size_t)it * H * F, b_vupd2 + (size_t)it * F,
        w_cupd1 + (size_t)it * H * H, b_cupd1 + (size_t)it * H,
        w_cupd2 + (size_t)it * H * F, b_cupd2 + (size_t)it * F,
        outv, outc, it == 1 ? 1 : 0);
  }
}